// Round 1
// baseline (1503.797 us; speedup 1.0000x reference)
//
#include <hip/hip_runtime.h>
#include <hip/hip_bf16.h>
#include <math.h>

#define DIMX   1024
#define HEADS  16
#define DH     64
#define NB     8
#define NSEQ   1024
#define ROWS   (NB * NSEQ)        // 8192
#define QKVW   (3 * DIMX)         // 3072

// ---------------------------------------------------------------------------
// Kernel 1: LayerNorm. One block (256 thr) per row of 1024.
// ---------------------------------------------------------------------------
__global__ __launch_bounds__(256) void ln_kernel(const float* __restrict__ x,
                                                 const float* __restrict__ gamma,
                                                 float* __restrict__ xn) {
    int row = blockIdx.x;
    const float* xr = x + (size_t)row * DIMX;
    float* xo = xn + (size_t)row * DIMX;
    int t = threadIdx.x;

    float4 v = ((const float4*)xr)[t];
    float s  = v.x + v.y + v.z + v.w;
    float ss = v.x*v.x + v.y*v.y + v.z*v.z + v.w*v.w;

    // wave (64) reduce then cross-wave via LDS
    #pragma unroll
    for (int o = 32; o > 0; o >>= 1) {
        s  += __shfl_down(s, o);
        ss += __shfl_down(ss, o);
    }
    __shared__ float sbuf[4], ssbuf[4];
    int lane = t & 63, wid = t >> 6;
    if (lane == 0) { sbuf[wid] = s; ssbuf[wid] = ss; }
    __syncthreads();
    if (t == 0) {
        float a = 0.f, b2 = 0.f;
        for (int i = 0; i < 4; i++) { a += sbuf[i]; b2 += ssbuf[i]; }
        sbuf[0] = a; ssbuf[0] = b2;
    }
    __syncthreads();
    float mean = sbuf[0] * (1.0f / DIMX);
    float var  = ssbuf[0] * (1.0f / DIMX) - mean * mean;
    float rstd = rsqrtf(var + 1e-5f);

    float4 g = ((const float4*)gamma)[t];
    float4 o;
    o.x = (v.x - mean) * rstd * g.x;
    o.y = (v.y - mean) * rstd * g.y;
    o.z = (v.z - mean) * rstd * g.z;
    o.w = (v.w - mean) * rstd * g.w;
    ((float4*)xo)[t] = o;
}

// ---------------------------------------------------------------------------
// Kernel 2: fp32 SGEMM  C[M][N] = A[M][K] @ B[K][N], row-major, 128x128 tile,
// BK=8, 256 threads, 8x8 microtile per thread. M%128==0, N%128==0, K%8==0.
// ---------------------------------------------------------------------------
#define BM 128
#define BN 128
#define BK 8

__global__ __launch_bounds__(256) void sgemm(const float* __restrict__ A,
                                             const float* __restrict__ Bm,
                                             float* __restrict__ C,
                                             int M, int Nn, int K) {
    __shared__ float As[BK][BM + 4];   // stored transposed: As[k][m]
    __shared__ float Bs[BK][BN + 4];   // natural: Bs[k][n]

    int t  = threadIdx.x;
    int tx = t & 15, ty = t >> 4;
    int m0 = blockIdx.y * BM, n0 = blockIdx.x * BN;

    float acc[8][8] = {};

    for (int k0 = 0; k0 < K; k0 += BK) {
        // A tile: 128 rows x 8 cols = 256 float4. thread t -> row t/2, colgrp t%2
        {
            int r = t >> 1, c = (t & 1) * 4;
            float4 a = *(const float4*)(A + (size_t)(m0 + r) * K + k0 + c);
            As[c + 0][r] = a.x; As[c + 1][r] = a.y;
            As[c + 2][r] = a.z; As[c + 3][r] = a.w;
        }
        // B tile: 8 rows x 128 cols = 256 float4. thread t -> row t/32, col (t%32)*4
        {
            int br = t >> 5, bc = (t & 31) * 4;
            float4 b = *(const float4*)(Bm + (size_t)(k0 + br) * Nn + n0 + bc);
            *(float4*)&Bs[br][bc] = b;
        }
        __syncthreads();

        #pragma unroll
        for (int kk = 0; kk < BK; kk++) {
            float a[8], b[8];
            #pragma unroll
            for (int i = 0; i < 8; i++) a[i] = As[kk][ty * 8 + i];
            #pragma unroll
            for (int j = 0; j < 8; j++) b[j] = Bs[kk][tx * 8 + j];
            #pragma unroll
            for (int i = 0; i < 8; i++)
                #pragma unroll
                for (int j = 0; j < 8; j++)
                    acc[i][j] += a[i] * b[j];
        }
        __syncthreads();
    }

    #pragma unroll
    for (int i = 0; i < 8; i++) {
        float* cp = C + (size_t)(m0 + ty * 8 + i) * Nn + n0 + tx * 8;
        float4 v0 = { acc[i][0], acc[i][1], acc[i][2], acc[i][3] };
        float4 v1 = { acc[i][4], acc[i][5], acc[i][6], acc[i][7] };
        ((float4*)cp)[0] = v0;
        ((float4*)cp)[1] = v1;
    }
}

// ---------------------------------------------------------------------------
// Kernel 3: RMS-ish norm (F.normalize * sqrt(64) * gamma) on q,k in-place.
// One 64-lane wave per (row, head, q|k) segment of 64 elems. 4 waves/block.
// ---------------------------------------------------------------------------
__global__ __launch_bounds__(256) void rms_kernel(float* __restrict__ qkv,
                                                  const float* __restrict__ qg,
                                                  const float* __restrict__ kg) {
    int t = threadIdx.x;
    int lane = t & 63, w = t >> 6;
    long seg = (long)blockIdx.x * 4 + w;   // (row*16 + h)*2 + which
    int which = (int)(seg & 1);
    long rh = seg >> 1;
    int h = (int)(rh & 15);
    long row = rh >> 4;

    float* p = qkv + (size_t)row * QKVW + which * DIMX + h * DH + lane;
    float v = *p;
    float sq = v * v;
    #pragma unroll
    for (int o = 1; o < 64; o <<= 1) sq += __shfl_xor(sq, o);
    float nrm = sqrtf(sq);
    float scale = 8.0f / fmaxf(nrm, 1e-12f);   // sqrt(DH)=8
    const float* g = which ? kg : qg;
    *p = v * scale * g[h * DH + lane];
}

// ---------------------------------------------------------------------------
// Kernel 4: flash attention, fp32. BQ=64 q-rows per block, k-tiles of 64.
// 256 threads, thread (ty,tx) owns 4x4 of the 64x64 score tile.
// Reads normed q,k,v from qkv buffer; writes pre-projection O [8192][1024].
// ---------------------------------------------------------------------------
__global__ __launch_bounds__(256) void flash_kernel(const float* __restrict__ qkv,
                                                    float* __restrict__ obuf) {
    __shared__ float QsT[DH][64 + 4];   // [d][r]
    __shared__ float KsT[DH][64 + 4];   // [d][c]
    __shared__ float Vs[64][DH + 4];    // [c][x]
    __shared__ float Ps[64][64 + 4];    // [r][c]

    int bh = blockIdx.x >> 4;          // 0..127
    int qt = blockIdx.x & 15;
    int b  = bh >> 4;
    int h  = bh & 15;

    int t  = threadIdx.x;
    int tx = t & 15, ty = t >> 4;

    const size_t rowbase = (size_t)(b * NSEQ) * QKVW + h * DH;
    const float* qbase = qkv + rowbase;                // + row*QKVW + d
    const float* kbase = qkv + rowbase + DIMX;
    const float* vbase = qkv + rowbase + 2 * DIMX;

    // load Q tile (transposed into LDS)
    #pragma unroll
    for (int u = 0; u < 4; u++) {
        int f = t + u * 256;               // 0..1023
        int r = f >> 4, c4 = (f & 15) * 4;
        float4 q4 = *(const float4*)(qbase + (size_t)(qt * 64 + r) * QKVW + c4);
        QsT[c4 + 0][r] = q4.x; QsT[c4 + 1][r] = q4.y;
        QsT[c4 + 2][r] = q4.z; QsT[c4 + 3][r] = q4.w;
    }

    float o[4][4] = {};
    float m_i[4], l_i[4];
    #pragma unroll
    for (int i = 0; i < 4; i++) { m_i[i] = -INFINITY; l_i[i] = 0.f; }

    for (int kt = 0; kt < 16; kt++) {
        // load K (transposed) and V (natural) tiles
        #pragma unroll
        for (int u = 0; u < 4; u++) {
            int f = t + u * 256;
            int r = f >> 4, c4 = (f & 15) * 4;
            float4 k4 = *(const float4*)(kbase + (size_t)(kt * 64 + r) * QKVW + c4);
            KsT[c4 + 0][r] = k4.x; KsT[c4 + 1][r] = k4.y;
            KsT[c4 + 2][r] = k4.z; KsT[c4 + 3][r] = k4.w;
            float4 v4 = *(const float4*)(vbase + (size_t)(kt * 64 + r) * QKVW + c4);
            *(float4*)&Vs[r][c4] = v4;
        }
        __syncthreads();

        // s = Q . K^T (4x4 per thread)
        float s[4][4] = {};
        #pragma unroll 8
        for (int d = 0; d < DH; d++) {
            float a[4], bb[4];
            #pragma unroll
            for (int i = 0; i < 4; i++) a[i]  = QsT[d][ty * 4 + i];
            #pragma unroll
            for (int j = 0; j < 4; j++) bb[j] = KsT[d][tx * 4 + j];
            #pragma unroll
            for (int i = 0; i < 4; i++)
                #pragma unroll
                for (int j = 0; j < 4; j++)
                    s[i][j] += a[i] * bb[j];
        }

        // online softmax update (rows live across the 16 tx lanes)
        #pragma unroll
        for (int i = 0; i < 4; i++) {
            float rmax = fmaxf(fmaxf(s[i][0], s[i][1]), fmaxf(s[i][2], s[i][3]));
            #pragma unroll
            for (int o2 = 1; o2 < 16; o2 <<= 1) rmax = fmaxf(rmax, __shfl_xor(rmax, o2, 16));
            float mnew = fmaxf(m_i[i], rmax);
            float alpha = expf(m_i[i] - mnew);
            float rsum = 0.f;
            #pragma unroll
            for (int j = 0; j < 4; j++) {
                s[i][j] = expf(s[i][j] - mnew);
                rsum += s[i][j];
            }
            #pragma unroll
            for (int o2 = 1; o2 < 16; o2 <<= 1) rsum += __shfl_xor(rsum, o2, 16);
            l_i[i] = l_i[i] * alpha + rsum;
            m_i[i] = mnew;
            #pragma unroll
            for (int j = 0; j < 4; j++) o[i][j] *= alpha;
        }

        // stash P
        #pragma unroll
        for (int i = 0; i < 4; i++) {
            float4 p4 = { s[i][0], s[i][1], s[i][2], s[i][3] };
            *(float4*)&Ps[ty * 4 + i][tx * 4] = p4;
        }
        __syncthreads();

        // O += P . V
        #pragma unroll 8
        for (int c = 0; c < 64; c++) {
            float a[4], bb[4];
            #pragma unroll
            for (int i = 0; i < 4; i++) a[i]  = Ps[ty * 4 + i][c];
            #pragma unroll
            for (int j = 0; j < 4; j++) bb[j] = Vs[c][tx * 4 + j];
            #pragma unroll
            for (int i = 0; i < 4; i++)
                #pragma unroll
                for (int j = 0; j < 4; j++)
                    o[i][j] += a[i] * bb[j];
        }
        __syncthreads();
    }

    // epilogue: normalize and write O (layout [b*1024+n][h*64+x])
    #pragma unroll
    for (int i = 0; i < 4; i++) {
        float inv = 1.0f / l_i[i];
        int gr = b * NSEQ + qt * 64 + ty * 4 + i;
        float4 o4 = { o[i][0] * inv, o[i][1] * inv, o[i][2] * inv, o[i][3] * inv };
        *(float4*)(obuf + (size_t)gr * DIMX + h * DH + tx * 4) = o4;
    }
}

// ---------------------------------------------------------------------------
extern "C" void kernel_launch(void* const* d_in, const int* in_sizes, int n_in,
                              void* d_out, int out_size, void* d_ws, size_t ws_size,
                              hipStream_t stream) {
    const float* x     = (const float*)d_in[0];
    const float* ln_g  = (const float*)d_in[1];
    const float* q_g   = (const float*)d_in[2];
    const float* k_g   = (const float*)d_in[3];
    const float* w_qkv = (const float*)d_in[4];
    const float* w_out = (const float*)d_in[5];
    float* out = (float*)d_out;

    float* xn   = (float*)d_ws;                       // 8192*1024
    float* qkv  = xn  + (size_t)ROWS * DIMX;          // 8192*3072
    float* obuf = qkv + (size_t)ROWS * QKVW;          // 8192*1024

    ln_kernel<<<ROWS, 256, 0, stream>>>(x, ln_g, xn);

    dim3 g1(QKVW / BN, ROWS / BM);
    sgemm<<<g1, 256, 0, stream>>>(xn, w_qkv, qkv, ROWS, QKVW, DIMX);

    rms_kernel<<<(ROWS * HEADS * 2) / 4, 256, 0, stream>>>(qkv, q_g, k_g);

    flash_kernel<<<NB * HEADS * (NSEQ / 64), 256, 0, stream>>>(qkv, obuf);

    dim3 g2(DIMX / BN, ROWS / BM);
    sgemm<<<g2, 256, 0, stream>>>(obuf, w_out, out, ROWS, DIMX, DIMX);
}

// Round 2
// 377.700 us; speedup vs baseline: 3.9815x; 3.9815x over previous
//
#include <hip/hip_runtime.h>
#include <hip/hip_bf16.h>
#include <math.h>

#define DIMX   1024
#define HEADS  16
#define DH     64
#define NB     8
#define NSEQ   1024
#define ROWS   (NB * NSEQ)        // 8192
#define QKVW   (3 * DIMX)         // 3072

typedef _Float16 half8 __attribute__((ext_vector_type(8)));
typedef _Float16 half4 __attribute__((ext_vector_type(4)));
typedef float floatx4 __attribute__((ext_vector_type(4)));

// ---------------------------------------------------------------------------
// Kernel 1: LayerNorm -> fp16 output. One block (256 thr) per row of 1024.
// ---------------------------------------------------------------------------
__global__ __launch_bounds__(256) void ln_kernel(const float* __restrict__ x,
                                                 const float* __restrict__ gamma,
                                                 _Float16* __restrict__ xn) {
    int row = blockIdx.x;
    const float* xr = x + (size_t)row * DIMX;
    _Float16* xo = xn + (size_t)row * DIMX;
    int t = threadIdx.x;

    float4 v = ((const float4*)xr)[t];
    float s  = v.x + v.y + v.z + v.w;
    float ss = v.x*v.x + v.y*v.y + v.z*v.z + v.w*v.w;

    #pragma unroll
    for (int o = 32; o > 0; o >>= 1) {
        s  += __shfl_down(s, o);
        ss += __shfl_down(ss, o);
    }
    __shared__ float sbuf[4], ssbuf[4];
    int lane = t & 63, wid = t >> 6;
    if (lane == 0) { sbuf[wid] = s; ssbuf[wid] = ss; }
    __syncthreads();
    if (t == 0) {
        float a = 0.f, b2 = 0.f;
        for (int i = 0; i < 4; i++) { a += sbuf[i]; b2 += ssbuf[i]; }
        sbuf[0] = a; ssbuf[0] = b2;
    }
    __syncthreads();
    float mean = sbuf[0] * (1.0f / DIMX);
    float var  = ssbuf[0] * (1.0f / DIMX) - mean * mean;
    float rstd = rsqrtf(var + 1e-5f);

    float4 g = ((const float4*)gamma)[t];
    half4 o;
    o.x = (_Float16)((v.x - mean) * rstd * g.x);
    o.y = (_Float16)((v.y - mean) * rstd * g.y);
    o.z = (_Float16)((v.z - mean) * rstd * g.z);
    o.w = (_Float16)((v.w - mean) * rstd * g.w);
    *(half4*)(xo + t * 4) = o;
}

// ---------------------------------------------------------------------------
// Kernel 2: weight transpose fp32 [K][N] -> fp16 [N][K]
// ---------------------------------------------------------------------------
__global__ __launch_bounds__(256) void wtrans(const float* __restrict__ W,
                                              _Float16* __restrict__ WT,
                                              int K, int N) {
    __shared__ float tile[32][33];
    int n0 = blockIdx.x * 32, k0 = blockIdx.y * 32;
    int tx = threadIdx.x & 31, ty = threadIdx.x >> 5;  // 32 x 8
    #pragma unroll
    for (int i = 0; i < 32; i += 8)
        tile[ty + i][tx] = W[(size_t)(k0 + ty + i) * N + n0 + tx];
    __syncthreads();
    #pragma unroll
    for (int i = 0; i < 32; i += 8)
        WT[(size_t)(n0 + ty + i) * K + k0 + tx] = (_Float16)tile[tx][ty + i];
}

// ---------------------------------------------------------------------------
// Kernel 3: fp16 MFMA GEMM  C[M][N] = A[M][K] @ BT[N][K]^T, C fp32.
// 128x128 block tile, BK=32, 4 waves each computing 64x64 via 4x4 frags of
// 16x16x32. M%128==0, N%128==0, K%32==0.
// ---------------------------------------------------------------------------
__global__ __launch_bounds__(256) void hgemm(const _Float16* __restrict__ A,
                                             const _Float16* __restrict__ BT,
                                             float* __restrict__ C,
                                             int M, int N, int K) {
    __shared__ _Float16 As[128][40];   // 32 k + 8 pad
    __shared__ _Float16 Bs[128][40];

    int t = threadIdx.x;
    int wave = t >> 6, lane = t & 63;
    int quad = lane >> 4, l16 = lane & 15;
    int wm = (wave >> 1) * 64, wn = (wave & 1) * 64;
    size_t m0 = (size_t)blockIdx.y * 128, n0 = (size_t)blockIdx.x * 128;

    floatx4 acc[4][4] = {};   // [mf][nf]

    int srow = t >> 1, sc = (t & 1) * 16;   // staging: 32B per thread
    const _Float16* ag = A  + (m0 + srow) * (size_t)K + sc;
    const _Float16* bg = BT + (n0 + srow) * (size_t)K + sc;

    for (int k0 = 0; k0 < K; k0 += 32) {
        half8 a0 = *(const half8*)(ag + k0);
        half8 a1 = *(const half8*)(ag + k0 + 8);
        half8 b0 = *(const half8*)(bg + k0);
        half8 b1 = *(const half8*)(bg + k0 + 8);
        *(half8*)&As[srow][sc]     = a0;
        *(half8*)&As[srow][sc + 8] = a1;
        *(half8*)&Bs[srow][sc]     = b0;
        *(half8*)&Bs[srow][sc + 8] = b1;
        __syncthreads();

        half8 af[4], bf[4];
        #pragma unroll
        for (int mf = 0; mf < 4; mf++)
            af[mf] = *(const half8*)&As[wm + mf * 16 + l16][quad * 8];
        #pragma unroll
        for (int nf = 0; nf < 4; nf++)
            bf[nf] = *(const half8*)&Bs[wn + nf * 16 + l16][quad * 8];

        #pragma unroll
        for (int mf = 0; mf < 4; mf++)
            #pragma unroll
            for (int nf = 0; nf < 4; nf++)
                acc[mf][nf] = __builtin_amdgcn_mfma_f32_16x16x32_f16(
                    af[mf], bf[nf], acc[mf][nf], 0, 0, 0);
        __syncthreads();
    }

    #pragma unroll
    for (int mf = 0; mf < 4; mf++) {
        #pragma unroll
        for (int nf = 0; nf < 4; nf++) {
            #pragma unroll
            for (int r = 0; r < 4; r++) {
                size_t row = m0 + wm + mf * 16 + quad * 4 + r;
                size_t col = n0 + wn + nf * 16 + l16;
                C[row * N + col] = acc[mf][nf][r];
            }
        }
    }
}

// ---------------------------------------------------------------------------
// Kernel 4: RMS norm q,k + fp16 repack to per-head layout.
// qf/kf/vf: [bh=b*16+h][n][64] fp16. One wave per (row, h).
// ---------------------------------------------------------------------------
__global__ __launch_bounds__(256) void rms_kernel(const float* __restrict__ qkv,
                                                  const float* __restrict__ qg,
                                                  const float* __restrict__ kg,
                                                  _Float16* __restrict__ qf,
                                                  _Float16* __restrict__ kf,
                                                  _Float16* __restrict__ vf) {
    int t = threadIdx.x;
    int lane = t & 63, w = t >> 6;
    long seg = (long)blockIdx.x * 4 + w;   // row*16 + h
    int h = (int)(seg & 15);
    long row = seg >> 4;
    int b = (int)(row >> 10), n = (int)(row & 1023);
    size_t dst = (((size_t)(b * 16 + h)) * 1024 + n) * 64 + lane;
    const float* src = qkv + (size_t)row * QKVW + h * DH + lane;

    float q = src[0];
    float k = src[DIMX];
    float v = src[2 * DIMX];

    float sq = q * q, sk = k * k;
    #pragma unroll
    for (int o = 1; o < 64; o <<= 1) {
        sq += __shfl_xor(sq, o);
        sk += __shfl_xor(sk, o);
    }
    float qs = 8.0f / fmaxf(sqrtf(sq), 1e-12f);
    float ks = 8.0f / fmaxf(sqrtf(sk), 1e-12f);
    qf[dst] = (_Float16)(q * qs * qg[h * DH + lane]);
    kf[dst] = (_Float16)(k * ks * kg[h * DH + lane]);
    vf[dst] = (_Float16)v;
}

// ---------------------------------------------------------------------------
// Kernel 5: flash attention with fp16 MFMA. One block per (bh, qtile of 64).
// 4 waves; wave owns 16 q-rows, iterates 16 k-tiles of 64. Online softmax.
// Writes obuf [8192][1024] fp16.
// ---------------------------------------------------------------------------
__global__ __launch_bounds__(256) void flash_kernel(const _Float16* __restrict__ qf,
                                                    const _Float16* __restrict__ kf,
                                                    const _Float16* __restrict__ vf,
                                                    _Float16* __restrict__ obuf) {
    __shared__ _Float16 Ks[64][72];        // [kcol][dh]
    __shared__ _Float16 VTs[64][72];       // [dh][kcol]
    __shared__ _Float16 Ps[4][16][72];     // per-wave P [qrow][kcol]

    int t = threadIdx.x;
    int wave = t >> 6, lane = t & 63;
    int quad = lane >> 4, l16 = lane & 15;
    int bh = blockIdx.x >> 4, qt = blockIdx.x & 15;

    const _Float16* qb = qf + ((size_t)bh * 1024 + qt * 64) * 64;
    const _Float16* kb = kf + (size_t)bh * 65536;
    const _Float16* vb = vf + (size_t)bh * 65536;

    // Q fragments (A-layout), loaded once from global
    half8 aq[2];
    {
        const _Float16* qrow = qb + (wave * 16 + l16) * 64;
        aq[0] = *(const half8*)(qrow + quad * 8);
        aq[1] = *(const half8*)(qrow + 32 + quad * 8);
    }

    floatx4 o[4] = {};        // [nf over dh], C-layout rows = quad*4+r
    float m_i[4], l_i[4];
    #pragma unroll
    for (int r = 0; r < 4; r++) { m_i[r] = -INFINITY; l_i[r] = 0.f; }

    int sr = t & 63, sh = t >> 6;   // staging: row, 16-elem chunk

    for (int kt = 0; kt < 16; kt++) {
        // stage K natural, V transposed
        {
            const _Float16* ksrc = kb + (size_t)(kt * 64 + sr) * 64 + sh * 16;
            *(half8*)&Ks[sr][sh * 16]     = *(const half8*)ksrc;
            *(half8*)&Ks[sr][sh * 16 + 8] = *(const half8*)(ksrc + 8);
            const _Float16* vsrc = vb + (size_t)(kt * 64 + sr) * 64 + sh * 16;
            half8 v0 = *(const half8*)vsrc;
            half8 v1 = *(const half8*)(vsrc + 8);
            #pragma unroll
            for (int i = 0; i < 8; i++) VTs[sh * 16 + i][sr] = v0[i];
            #pragma unroll
            for (int i = 0; i < 8; i++) VTs[sh * 16 + 8 + i][sr] = v1[i];
        }
        __syncthreads();

        // S = Q K^T : 16 x 64 strip per wave
        floatx4 s[4] = {};
        #pragma unroll
        for (int kc = 0; kc < 2; kc++) {
            #pragma unroll
            for (int nf = 0; nf < 4; nf++) {
                half8 bk = *(const half8*)&Ks[nf * 16 + l16][kc * 32 + quad * 8];
                s[nf] = __builtin_amdgcn_mfma_f32_16x16x32_f16(aq[kc], bk, s[nf], 0, 0, 0);
            }
        }

        // online softmax (rows = quad*4+r, cols across nf and l16)
        #pragma unroll
        for (int r = 0; r < 4; r++) {
            float mx = fmaxf(fmaxf(s[0][r], s[1][r]), fmaxf(s[2][r], s[3][r]));
            #pragma unroll
            for (int o2 = 1; o2 < 16; o2 <<= 1) mx = fmaxf(mx, __shfl_xor(mx, o2));
            float mnew = fmaxf(m_i[r], mx);
            float alpha = __expf(m_i[r] - mnew);
            float sum = 0.f;
            #pragma unroll
            for (int nf = 0; nf < 4; nf++) {
                float p = __expf(s[nf][r] - mnew);
                s[nf][r] = p;
                sum += p;
            }
            #pragma unroll
            for (int o2 = 1; o2 < 16; o2 <<= 1) sum += __shfl_xor(sum, o2);
            l_i[r] = l_i[r] * alpha + sum;
            m_i[r] = mnew;
            #pragma unroll
            for (int nf = 0; nf < 4; nf++) o[nf][r] *= alpha;
        }

        // P -> LDS (per-wave buffer; wave-internal ordering, no barrier)
        #pragma unroll
        for (int nf = 0; nf < 4; nf++)
            #pragma unroll
            for (int r = 0; r < 4; r++)
                Ps[wave][quad * 4 + r][nf * 16 + l16] = (_Float16)s[nf][r];

        // O += P V
        #pragma unroll
        for (int kc = 0; kc < 2; kc++) {
            half8 ap = *(const half8*)&Ps[wave][l16][kc * 32 + quad * 8];
            #pragma unroll
            for (int nf = 0; nf < 4; nf++) {
                half8 bv = *(const half8*)&VTs[nf * 16 + l16][kc * 32 + quad * 8];
                o[nf] = __builtin_amdgcn_mfma_f32_16x16x32_f16(ap, bv, o[nf], 0, 0, 0);
            }
        }
        __syncthreads();
    }

    // epilogue: normalize, write fp16 obuf [row][h*64+dh]
    int b = bh >> 4, h = bh & 15;
    #pragma unroll
    for (int r = 0; r < 4; r++) {
        float inv = 1.0f / l_i[r];
        size_t row = (size_t)b * 1024 + qt * 64 + wave * 16 + quad * 4 + r;
        #pragma unroll
        for (int nf = 0; nf < 4; nf++) {
            size_t col = h * 64 + nf * 16 + l16;
            obuf[row * 1024 + col] = (_Float16)(o[nf][r] * inv);
        }
    }
}

// ---------------------------------------------------------------------------
extern "C" void kernel_launch(void* const* d_in, const int* in_sizes, int n_in,
                              void* d_out, int out_size, void* d_ws, size_t ws_size,
                              hipStream_t stream) {
    const float* x     = (const float*)d_in[0];
    const float* ln_g  = (const float*)d_in[1];
    const float* q_g   = (const float*)d_in[2];
    const float* k_g   = (const float*)d_in[3];
    const float* w_qkv = (const float*)d_in[4];
    const float* w_out = (const float*)d_in[5];
    float* out = (float*)d_out;

    // workspace layout (160 MB, aliased by liveness):
    //   [0,16MB)    xn fp16  -> later obuf fp16
    //   [16,112MB)  qkv fp32 -> later woutT fp16 (2MB at base)
    //   [112,128MB) wqkvT fp16 (6MB) -> later qf fp16
    //   [128,144MB) kf fp16
    //   [144,160MB) vf fp16
    char* base = (char*)d_ws;
    _Float16* xn    = (_Float16*)(base);
    _Float16* obuf  = (_Float16*)(base);
    float*    qkv   = (float*)(base + (16ull << 20));
    _Float16* woutT = (_Float16*)(base + (16ull << 20));
    _Float16* wqkvT = (_Float16*)(base + (112ull << 20));
    _Float16* qf    = (_Float16*)(base + (112ull << 20));
    _Float16* kf    = (_Float16*)(base + (128ull << 20));
    _Float16* vf    = (_Float16*)(base + (144ull << 20));

    ln_kernel<<<ROWS, 256, 0, stream>>>(x, ln_g, xn);

    dim3 gt1(QKVW / 32, DIMX / 32);
    wtrans<<<gt1, 256, 0, stream>>>(w_qkv, wqkvT, DIMX, QKVW);

    dim3 g1(QKVW / 128, ROWS / 128);
    hgemm<<<g1, 256, 0, stream>>>(xn, wqkvT, qkv, ROWS, QKVW, DIMX);

    rms_kernel<<<(ROWS * HEADS) / 4, 256, 0, stream>>>(qkv, q_g, k_g, qf, kf, vf);

    dim3 gt2(DIMX / 32, DIMX / 32);
    wtrans<<<gt2, 256, 0, stream>>>(w_out, woutT, DIMX, DIMX);

    flash_kernel<<<NB * HEADS * (NSEQ / 64), 256, 0, stream>>>(qf, kf, vf, obuf);

    dim3 g2(DIMX / 128, ROWS / 128);
    hgemm<<<g2, 256, 0, stream>>>(obuf, woutT, out, ROWS, DIMX, DIMX);
}

// Round 3
// 342.090 us; speedup vs baseline: 4.3959x; 1.1041x over previous
//
#include <hip/hip_runtime.h>
#include <hip/hip_bf16.h>
#include <math.h>

#define DIMX   1024
#define HEADS  16
#define DH     64
#define NB     8
#define NSEQ   1024
#define ROWS   (NB * NSEQ)        // 8192
#define QKVW   (3 * DIMX)         // 3072

typedef _Float16 half8 __attribute__((ext_vector_type(8)));
typedef _Float16 half4 __attribute__((ext_vector_type(4)));
typedef float floatx4 __attribute__((ext_vector_type(4)));

// async global->LDS, 16B per lane. lptr must be wave-uniform; HW adds lane*16.
#define GLD_LDS16(gptr, lptr) __builtin_amdgcn_global_load_lds( \
    (const __attribute__((address_space(1))) void*)(gptr),      \
    (__attribute__((address_space(3))) void*)(lptr), 16, 0, 0)

// ---------------------------------------------------------------------------
// Kernel 1: LayerNorm -> fp16. One block (256 thr) per row of 1024.
// ---------------------------------------------------------------------------
__global__ __launch_bounds__(256) void ln_kernel(const float* __restrict__ x,
                                                 const float* __restrict__ gamma,
                                                 _Float16* __restrict__ xn) {
    int row = blockIdx.x;
    const float* xr = x + (size_t)row * DIMX;
    _Float16* xo = xn + (size_t)row * DIMX;
    int t = threadIdx.x;

    float4 v = ((const float4*)xr)[t];
    float s  = v.x + v.y + v.z + v.w;
    float ss = v.x*v.x + v.y*v.y + v.z*v.z + v.w*v.w;

    #pragma unroll
    for (int o = 32; o > 0; o >>= 1) {
        s  += __shfl_down(s, o);
        ss += __shfl_down(ss, o);
    }
    __shared__ float sbuf[4], ssbuf[4];
    int lane = t & 63, wid = t >> 6;
    if (lane == 0) { sbuf[wid] = s; ssbuf[wid] = ss; }
    __syncthreads();
    if (t == 0) {
        float a = 0.f, b2 = 0.f;
        for (int i = 0; i < 4; i++) { a += sbuf[i]; b2 += ssbuf[i]; }
        sbuf[0] = a; ssbuf[0] = b2;
    }
    __syncthreads();
    float mean = sbuf[0] * (1.0f / DIMX);
    float var  = ssbuf[0] * (1.0f / DIMX) - mean * mean;
    float rstd = rsqrtf(var + 1e-5f);

    float4 g = ((const float4*)gamma)[t];
    half4 o;
    o.x = (_Float16)((v.x - mean) * rstd * g.x);
    o.y = (_Float16)((v.y - mean) * rstd * g.y);
    o.z = (_Float16)((v.z - mean) * rstd * g.z);
    o.w = (_Float16)((v.w - mean) * rstd * g.w);
    *(half4*)(xo + t * 4) = o;
}

// ---------------------------------------------------------------------------
// Kernel 2: weight transpose fp32 [K][N] -> fp16 [N][K]
// ---------------------------------------------------------------------------
__global__ __launch_bounds__(256) void wtrans(const float* __restrict__ W,
                                              _Float16* __restrict__ WT,
                                              int K, int N) {
    __shared__ float tile[32][33];
    int n0 = blockIdx.x * 32, k0 = blockIdx.y * 32;
    int tx = threadIdx.x & 31, ty = threadIdx.x >> 5;  // 32 x 8
    #pragma unroll
    for (int i = 0; i < 32; i += 8)
        tile[ty + i][tx] = W[(size_t)(k0 + ty + i) * N + n0 + tx];
    __syncthreads();
    #pragma unroll
    for (int i = 0; i < 32; i += 8)
        WT[(size_t)(n0 + ty + i) * K + k0 + tx] = (_Float16)tile[tx][ty + i];
}

// ---------------------------------------------------------------------------
// Kernel 3: m97-style fp16 MFMA GEMM. C[M][N] = A[M][K] @ BT[N][K]^T.
// 128x128 tile, BK=32, global_load_lds width-16 staging into unpadded
// [128][32] LDS tiles. 4 waves x 64x64. Templated output type.
// ---------------------------------------------------------------------------
template <typename CT>
__global__ __launch_bounds__(256) void hgemm(const _Float16* __restrict__ A,
                                             const _Float16* __restrict__ BT,
                                             CT* __restrict__ C,
                                             int M, int N, int K) {
    __shared__ _Float16 As[128 * 32];
    __shared__ _Float16 Bs[128 * 32];

    int t = threadIdx.x;
    int wave = t >> 6, lane = t & 63;
    int quad = lane >> 4, l16 = lane & 15;
    int wm = (wave >> 1) * 64, wn = (wave & 1) * 64;
    size_t m0 = (size_t)blockIdx.y * 128, n0 = (size_t)blockIdx.x * 128;

    floatx4 acc[4][4] = {};

    int sr = t >> 2, sg = t & 3;          // row 0..63, 16B-group 0..3
    const _Float16* ag  = A  + (m0 + sr) * (size_t)K + sg * 8;
    const _Float16* bg  = BT + (n0 + sr) * (size_t)K + sg * 8;
    const _Float16* ag2 = ag + (size_t)64 * K;
    const _Float16* bg2 = bg + (size_t)64 * K;
    char* lA = (char*)As + (t >> 6) * 1024;
    char* lB = (char*)Bs + (t >> 6) * 1024;

    for (int k0 = 0; k0 < K; k0 += 32) {
        GLD_LDS16(ag  + k0, lA);
        GLD_LDS16(ag2 + k0, lA + 4096);
        GLD_LDS16(bg  + k0, lB);
        GLD_LDS16(bg2 + k0, lB + 4096);
        __syncthreads();

        half8 af[4], bf[4];
        #pragma unroll
        for (int mf = 0; mf < 4; mf++)
            af[mf] = *(const half8*)&As[(wm + mf * 16 + l16) * 32 + quad * 8];
        #pragma unroll
        for (int nf = 0; nf < 4; nf++)
            bf[nf] = *(const half8*)&Bs[(wn + nf * 16 + l16) * 32 + quad * 8];

        #pragma unroll
        for (int mf = 0; mf < 4; mf++)
            #pragma unroll
            for (int nf = 0; nf < 4; nf++)
                acc[mf][nf] = __builtin_amdgcn_mfma_f32_16x16x32_f16(
                    af[mf], bf[nf], acc[mf][nf], 0, 0, 0);
        __syncthreads();
    }

    #pragma unroll
    for (int mf = 0; mf < 4; mf++)
        #pragma unroll
        for (int nf = 0; nf < 4; nf++)
            #pragma unroll
            for (int r = 0; r < 4; r++) {
                size_t row = m0 + wm + mf * 16 + quad * 4 + r;
                size_t col = n0 + wn + nf * 16 + l16;
                C[row * N + col] = (CT)acc[mf][nf][r];
            }
}

// ---------------------------------------------------------------------------
// Kernel 4: RMS norm q,k (reads fp16 qkv) -> qf/kf [bh][n][64] fp16.
// One wave per (row, h).
// ---------------------------------------------------------------------------
__global__ __launch_bounds__(256) void rms_kernel(const _Float16* __restrict__ qkv,
                                                  const float* __restrict__ qg,
                                                  const float* __restrict__ kg,
                                                  _Float16* __restrict__ qf,
                                                  _Float16* __restrict__ kf) {
    int t = threadIdx.x;
    int lane = t & 63, w = t >> 6;
    long seg = (long)blockIdx.x * 4 + w;   // row*16 + h
    int h = (int)(seg & 15);
    long row = seg >> 4;
    int b = (int)(row >> 10), n = (int)(row & 1023);
    size_t dst = (((size_t)(b * 16 + h)) * 1024 + n) * 64 + lane;
    const _Float16* src = qkv + (size_t)row * QKVW + h * DH + lane;

    float q = (float)src[0];
    float k = (float)src[DIMX];
    float sq = q * q, sk = k * k;
    #pragma unroll
    for (int o = 1; o < 64; o <<= 1) {
        sq += __shfl_xor(sq, o);
        sk += __shfl_xor(sk, o);
    }
    float qs = 8.0f / fmaxf(sqrtf(sq), 1e-12f);
    float ks = 8.0f / fmaxf(sqrtf(sk), 1e-12f);
    qf[dst] = (_Float16)(q * qs * qg[h * DH + lane]);
    kf[dst] = (_Float16)(k * ks * kg[h * DH + lane]);
}

// ---------------------------------------------------------------------------
// Kernel 5: V transpose: qkv fp16 [row][2048+h*64+d] -> vt[bh][kt][d=64][n=64]
// One block per (bh, kt) 64x64 tile.
// ---------------------------------------------------------------------------
__global__ __launch_bounds__(256) void vtrans(const _Float16* __restrict__ qkv,
                                              _Float16* __restrict__ vt) {
    __shared__ _Float16 tile[64][65];
    int blk = blockIdx.x;              // bh*16 + kt
    int bh = blk >> 4, kt = blk & 15;
    int b = bh >> 4, h = bh & 15;
    int t = threadIdx.x;

    #pragma unroll
    for (int i = 0; i < 2; i++) {
        int r = i * 32 + (t >> 3), g = t & 7;
        half8 v8 = *(const half8*)(qkv + ((size_t)(b * NSEQ) + kt * 64 + r) * QKVW
                                   + 2 * DIMX + h * 64 + g * 8);
        #pragma unroll
        for (int j = 0; j < 8; j++) tile[g * 8 + j][r] = v8[j];
    }
    __syncthreads();
    #pragma unroll
    for (int i = 0; i < 2; i++) {
        int d = i * 32 + (t >> 3), rg = t & 7;
        half8 o8;
        #pragma unroll
        for (int j = 0; j < 8; j++) o8[j] = tile[d][rg * 8 + j];
        *(half8*)(vt + ((size_t)blk * 64 + d) * 64 + rg * 8) = o8;
    }
}

// ---------------------------------------------------------------------------
// Kernel 6: flash attention. Block = (bh, qtile of 128). 4 waves, 2 strips of
// 16 q-rows each per wave. K-tiles of 64 staged via global_load_lds with
// XOR-8 16B-group swizzle (swizzle applied to GLOBAL source; LDS unpadded).
// Row-sum shuffles deferred to epilogue; only row-max reduced per tile.
// ---------------------------------------------------------------------------
__global__ __launch_bounds__(256) void flash_kernel(const _Float16* __restrict__ qf,
                                                    const _Float16* __restrict__ kf,
                                                    const _Float16* __restrict__ vt,
                                                    _Float16* __restrict__ obuf) {
    __shared__ _Float16 Ks[64 * 64];       // [kcol][dh], group-swizzled
    __shared__ _Float16 VTs[64 * 64];      // [dh][kcol], group-swizzled
    __shared__ _Float16 Ps[4][2][16][72];  // per-wave, per-strip P

    int t = threadIdx.x;
    int wave = t >> 6, lane = t & 63;
    int quad = lane >> 4, l16 = lane & 15;
    int bh = blockIdx.x >> 3, qt = blockIdx.x & 7;

    const _Float16* qb = qf + ((size_t)bh * 1024 + qt * 128) * 64;
    const _Float16* kb = kf + (size_t)bh * 65536;
    const _Float16* vb = vt + (size_t)bh * 65536;

    // Q A-frags from global (once): strip rows = wave*32 + st*16 + l16
    half8 aq[2][2];
    #pragma unroll
    for (int st = 0; st < 2; st++) {
        const _Float16* qrow = qb + (wave * 32 + st * 16 + l16) * 64;
        aq[st][0] = *(const half8*)(qrow + quad * 8);
        aq[st][1] = *(const half8*)(qrow + 32 + quad * 8);
    }

    floatx4 o[2][4] = {};
    float m_i[2][4], l_i[2][4];
    #pragma unroll
    for (int st = 0; st < 2; st++)
        #pragma unroll
        for (int r = 0; r < 4; r++) { m_i[st][r] = -INFINITY; l_i[st][r] = 0.f; }

    int sr = t >> 3;          // 0..31 (row within 32-row chunk)
    int sg = t & 7;           // 16B group within 128B row
    int swz = sg ^ (sr & 7);  // swizzled source group
    char* lK = (char*)Ks  + (t >> 6) * 1024;
    char* lV = (char*)VTs + (t >> 6) * 1024;

    for (int kt = 0; kt < 16; kt++) {
        const _Float16* kbt = kb + (size_t)kt * 64 * 64;
        const _Float16* vbt = vb + (size_t)kt * 64 * 64;
        #pragma unroll
        for (int i = 0; i < 2; i++) {
            GLD_LDS16(kbt + (i * 32 + sr) * 64 + swz * 8, lK + i * 4096);
            GLD_LDS16(vbt + (i * 32 + sr) * 64 + swz * 8, lV + i * 4096);
        }
        __syncthreads();

        #pragma unroll
        for (int st = 0; st < 2; st++) {
            // S = Q K^T (16 x 64 strip)
            floatx4 sc[4] = {};
            #pragma unroll
            for (int kc = 0; kc < 2; kc++) {
                #pragma unroll
                for (int nf = 0; nf < 4; nf++) {
                    half8 bk = *(const half8*)&Ks[(nf * 16 + l16) * 64
                                    + (((kc * 4 + quad) ^ (l16 & 7)) * 8)];
                    sc[nf] = __builtin_amdgcn_mfma_f32_16x16x32_f16(
                        aq[st][kc], bk, sc[nf], 0, 0, 0);
                }
            }

            // online softmax: row-max shuffle only; sum deferred per-lane
            #pragma unroll
            for (int r = 0; r < 4; r++) {
                float mx = fmaxf(fmaxf(sc[0][r], sc[1][r]), fmaxf(sc[2][r], sc[3][r]));
                #pragma unroll
                for (int o2 = 1; o2 < 16; o2 <<= 1) mx = fmaxf(mx, __shfl_xor(mx, o2));
                float mnew = fmaxf(m_i[st][r], mx);
                float alpha = __expf(m_i[st][r] - mnew);
                m_i[st][r] = mnew;
                float psum = 0.f;
                #pragma unroll
                for (int nf = 0; nf < 4; nf++) {
                    float p = __expf(sc[nf][r] - mnew);
                    sc[nf][r] = p;
                    psum += p;
                }
                l_i[st][r] = l_i[st][r] * alpha + psum;  // per-lane partial
                #pragma unroll
                for (int nf = 0; nf < 4; nf++) o[st][nf][r] *= alpha;
            }

            // P -> LDS (C-layout), wave-local
            #pragma unroll
            for (int nf = 0; nf < 4; nf++)
                #pragma unroll
                for (int r = 0; r < 4; r++)
                    Ps[wave][st][quad * 4 + r][nf * 16 + l16] = (_Float16)sc[nf][r];

            // O += P V
            #pragma unroll
            for (int kc = 0; kc < 2; kc++) {
                half8 ap = *(const half8*)&Ps[wave][st][l16][kc * 32 + quad * 8];
                #pragma unroll
                for (int nf = 0; nf < 4; nf++) {
                    half8 bv = *(const half8*)&VTs[(nf * 16 + l16) * 64
                                    + (((kc * 4 + quad) ^ (l16 & 7)) * 8)];
                    o[st][nf] = __builtin_amdgcn_mfma_f32_16x16x32_f16(
                        ap, bv, o[st][nf], 0, 0, 0);
                }
            }
        }
        __syncthreads();
    }

    // epilogue: reduce l across the 16-lane col group, normalize, store fp16
    int b = bh >> 4, h = bh & 15;
    #pragma unroll
    for (int st = 0; st < 2; st++)
        #pragma unroll
        for (int r = 0; r < 4; r++) {
            float lsum = l_i[st][r];
            #pragma unroll
            for (int o2 = 1; o2 < 16; o2 <<= 1) lsum += __shfl_xor(lsum, o2);
            float inv = 1.0f / lsum;
            size_t row = (size_t)b * NSEQ + qt * 128 + wave * 32 + st * 16 + quad * 4 + r;
            #pragma unroll
            for (int nf = 0; nf < 4; nf++)
                obuf[row * 1024 + h * 64 + nf * 16 + l16] =
                    (_Float16)(o[st][nf][r] * inv);
        }
}

// ---------------------------------------------------------------------------
extern "C" void kernel_launch(void* const* d_in, const int* in_sizes, int n_in,
                              void* d_out, int out_size, void* d_ws, size_t ws_size,
                              hipStream_t stream) {
    const float* x     = (const float*)d_in[0];
    const float* ln_g  = (const float*)d_in[1];
    const float* q_g   = (const float*)d_in[2];
    const float* k_g   = (const float*)d_in[3];
    const float* w_qkv = (const float*)d_in[4];
    const float* w_out = (const float*)d_in[5];
    float* out = (float*)d_out;

    // workspace (128 MB):
    //   [0,16)    xn fp16 / obuf fp16 (aliased: xn dead before flash writes)
    //   [16,64)   qkv fp16 (48 MB)
    //   [64,70)   wqkvT fp16 (6 MB)
    //   [72,74)   woutT fp16 (2 MB)
    //   [80,96)   qf, [96,112) kf, [112,128) vt
    char* base = (char*)d_ws;
    _Float16* xn    = (_Float16*)(base);
    _Float16* obuf  = (_Float16*)(base);
    _Float16* qkv   = (_Float16*)(base + (16ull << 20));
    _Float16* wqkvT = (_Float16*)(base + (64ull << 20));
    _Float16* woutT = (_Float16*)(base + (72ull << 20));
    _Float16* qf    = (_Float16*)(base + (80ull << 20));
    _Float16* kf    = (_Float16*)(base + (96ull << 20));
    _Float16* vt    = (_Float16*)(base + (112ull << 20));

    ln_kernel<<<ROWS, 256, 0, stream>>>(x, ln_g, xn);

    dim3 gt1(QKVW / 32, DIMX / 32);
    wtrans<<<gt1, 256, 0, stream>>>(w_qkv, wqkvT, DIMX, QKVW);

    dim3 g1(QKVW / 128, ROWS / 128);
    hgemm<_Float16><<<g1, 256, 0, stream>>>(xn, wqkvT, qkv, ROWS, QKVW, DIMX);

    rms_kernel<<<(ROWS * HEADS) / 4, 256, 0, stream>>>(qkv, q_g, k_g, qf, kf);

    vtrans<<<NB * HEADS * (NSEQ / 64), 256, 0, stream>>>(qkv, vt);

    dim3 gt2(DIMX / 32, DIMX / 32);
    wtrans<<<gt2, 256, 0, stream>>>(w_out, woutT, DIMX, DIMX);

    flash_kernel<<<NB * HEADS * (NSEQ / 128), 256, 0, stream>>>(qf, kf, vt, obuf);

    dim3 g2(DIMX / 128, ROWS / 128);
    hgemm<float><<<g2, 256, 0, stream>>>(obuf, woutT, out, ROWS, DIMX, DIMX);
}

// Round 4
// 288.675 us; speedup vs baseline: 5.2093x; 1.1850x over previous
//
#include <hip/hip_runtime.h>
#include <hip/hip_bf16.h>
#include <math.h>

#define DIMX   1024
#define HEADS  16
#define DH     64
#define NB     8
#define NSEQ   1024
#define ROWS   (NB * NSEQ)        // 8192
#define QKVW   (3 * DIMX)         // 3072

typedef _Float16 half8 __attribute__((ext_vector_type(8)));
typedef _Float16 half4 __attribute__((ext_vector_type(4)));
typedef float floatx4 __attribute__((ext_vector_type(4)));

// async global->LDS, 16B per lane. lptr must be wave-uniform; HW adds lane*16.
#define GLD_LDS16(gptr, lptr) __builtin_amdgcn_global_load_lds( \
    (const __attribute__((address_space(1))) void*)(gptr),      \
    (__attribute__((address_space(3))) void*)(lptr), 16, 0, 0)

// ---------------------------------------------------------------------------
// Kernel 1: LayerNorm -> fp16. One block (256 thr) per row of 1024.
// ---------------------------------------------------------------------------
__global__ __launch_bounds__(256) void ln_kernel(const float* __restrict__ x,
                                                 const float* __restrict__ gamma,
                                                 _Float16* __restrict__ xn) {
    int row = blockIdx.x;
    const float* xr = x + (size_t)row * DIMX;
    _Float16* xo = xn + (size_t)row * DIMX;
    int t = threadIdx.x;

    float4 v = ((const float4*)xr)[t];
    float s  = v.x + v.y + v.z + v.w;
    float ss = v.x*v.x + v.y*v.y + v.z*v.z + v.w*v.w;

    #pragma unroll
    for (int o = 32; o > 0; o >>= 1) {
        s  += __shfl_down(s, o);
        ss += __shfl_down(ss, o);
    }
    __shared__ float sbuf[4], ssbuf[4];
    int lane = t & 63, wid = t >> 6;
    if (lane == 0) { sbuf[wid] = s; ssbuf[wid] = ss; }
    __syncthreads();
    if (t == 0) {
        float a = 0.f, b2 = 0.f;
        for (int i = 0; i < 4; i++) { a += sbuf[i]; b2 += ssbuf[i]; }
        sbuf[0] = a; ssbuf[0] = b2;
    }
    __syncthreads();
    float mean = sbuf[0] * (1.0f / DIMX);
    float var  = ssbuf[0] * (1.0f / DIMX) - mean * mean;
    float rstd = rsqrtf(var + 1e-5f);

    float4 g = ((const float4*)gamma)[t];
    half4 o;
    o.x = (_Float16)((v.x - mean) * rstd * g.x);
    o.y = (_Float16)((v.y - mean) * rstd * g.y);
    o.z = (_Float16)((v.z - mean) * rstd * g.z);
    o.w = (_Float16)((v.w - mean) * rstd * g.w);
    *(half4*)(xo + t * 4) = o;
}

// ---------------------------------------------------------------------------
// Kernel 2: weight transpose fp32 [K][N] -> fp16 [N][K]
// ---------------------------------------------------------------------------
__global__ __launch_bounds__(256) void wtrans(const float* __restrict__ W,
                                              _Float16* __restrict__ WT,
                                              int K, int N) {
    __shared__ float tile[32][33];
    int n0 = blockIdx.x * 32, k0 = blockIdx.y * 32;
    int tx = threadIdx.x & 31, ty = threadIdx.x >> 5;  // 32 x 8
    #pragma unroll
    for (int i = 0; i < 32; i += 8)
        tile[ty + i][tx] = W[(size_t)(k0 + ty + i) * N + n0 + tx];
    __syncthreads();
    #pragma unroll
    for (int i = 0; i < 32; i += 8)
        WT[(size_t)(n0 + ty + i) * K + k0 + tx] = (_Float16)tile[tx][ty + i];
}

// ---------------------------------------------------------------------------
// Kernel 3: fp16 MFMA GEMM, BK=64, XOR-swizzled global_load_lds staging.
// C[M][N] = A[M][K] @ BT[N][K]^T. 128x128 tile, 4 waves x 64x64.
// LDS rows are 128B; slot g holds global 16B-group g^(row&7) -> 2-way banks.
// ---------------------------------------------------------------------------
template <typename CT>
__global__ __launch_bounds__(256) void hgemm(const _Float16* __restrict__ A,
                                             const _Float16* __restrict__ BT,
                                             CT* __restrict__ C,
                                             int M, int N, int K) {
    __shared__ _Float16 As[128 * 64];
    __shared__ _Float16 Bs[128 * 64];

    int t = threadIdx.x;
    int wave = t >> 6, lane = t & 63;
    int quad = lane >> 4, l16 = lane & 15;
    int wm = (wave >> 1) * 64, wn = (wave & 1) * 64;
    size_t m0 = (size_t)blockIdx.y * 128, n0 = (size_t)blockIdx.x * 128;

    floatx4 acc[4][4] = {};

    int sr = t >> 3, sg = t & 7;
    int swz = sg ^ (sr & 7);
    const _Float16* ag = A  + (m0 + sr) * (size_t)K + swz * 8;
    const _Float16* bg = BT + (n0 + sr) * (size_t)K + swz * 8;
    char* lA = (char*)As + (t >> 6) * 1024;
    char* lB = (char*)Bs + (t >> 6) * 1024;

    for (int k0 = 0; k0 < K; k0 += 64) {
        #pragma unroll
        for (int i = 0; i < 4; i++) {
            GLD_LDS16(ag + (size_t)(i * 32) * K + k0, lA + i * 4096);
            GLD_LDS16(bg + (size_t)(i * 32) * K + k0, lB + i * 4096);
        }
        __syncthreads();

        half8 af[2][4], bf[2][4];
        #pragma unroll
        for (int kk = 0; kk < 2; kk++) {
            #pragma unroll
            for (int mf = 0; mf < 4; mf++)
                af[kk][mf] = *(const half8*)&As[(wm + mf * 16 + l16) * 64
                                 + (((kk * 4 + quad) ^ (l16 & 7)) * 8)];
            #pragma unroll
            for (int nf = 0; nf < 4; nf++)
                bf[kk][nf] = *(const half8*)&Bs[(wn + nf * 16 + l16) * 64
                                 + (((kk * 4 + quad) ^ (l16 & 7)) * 8)];
        }

        #pragma unroll
        for (int kk = 0; kk < 2; kk++)
            #pragma unroll
            for (int mf = 0; mf < 4; mf++)
                #pragma unroll
                for (int nf = 0; nf < 4; nf++)
                    acc[mf][nf] = __builtin_amdgcn_mfma_f32_16x16x32_f16(
                        af[kk][mf], bf[kk][nf], acc[mf][nf], 0, 0, 0);
        __syncthreads();
    }

    #pragma unroll
    for (int mf = 0; mf < 4; mf++)
        #pragma unroll
        for (int nf = 0; nf < 4; nf++)
            #pragma unroll
            for (int r = 0; r < 4; r++) {
                size_t row = m0 + wm + mf * 16 + quad * 4 + r;
                size_t col = n0 + wn + nf * 16 + l16;
                C[row * N + col] = (CT)acc[mf][nf][r];
            }
}

// ---------------------------------------------------------------------------
// Kernel 4: fused RMS-norm(q,k) + repack + V-transpose.
// Block = (bh, nt): one 64-row chunk. qf/kf: [bh][n][64]; vt: [bh][nt][d][n].
// ---------------------------------------------------------------------------
__global__ __launch_bounds__(256) void rmsvt(const _Float16* __restrict__ qkv,
                                             const float* __restrict__ qg,
                                             const float* __restrict__ kg,
                                             _Float16* __restrict__ qf,
                                             _Float16* __restrict__ kf,
                                             _Float16* __restrict__ vt) {
    __shared__ _Float16 tile[64][72];
    int blk = blockIdx.x;              // bh*16 + nt
    int bh = blk >> 4, nt = blk & 15;
    int b = bh >> 4, h = bh & 15;
    int t = threadIdx.x;
    int r = t >> 2, cg = t & 3;        // row in chunk, 16-col group

    const _Float16* src = qkv + ((size_t)(b * NSEQ) + nt * 64 + r) * QKVW + h * 64 + cg * 16;
    size_t drow = ((size_t)bh * 1024 + nt * 64 + r) * 64 + cg * 16;

    // ---- q ----
    half8 q0 = *(const half8*)(src);
    half8 q1 = *(const half8*)(src + 8);
    float sq = 0.f;
    #pragma unroll
    for (int j = 0; j < 8; j++) { float a=(float)q0[j], b2=(float)q1[j]; sq += a*a + b2*b2; }
    sq += __shfl_xor(sq, 1); sq += __shfl_xor(sq, 2);
    float qs = 8.0f / fmaxf(sqrtf(sq), 1e-12f);
    half8 oq0, oq1;
    #pragma unroll
    for (int j = 0; j < 8; j++) {
        oq0[j] = (_Float16)((float)q0[j] * qs * qg[h * 64 + cg * 16 + j]);
        oq1[j] = (_Float16)((float)q1[j] * qs * qg[h * 64 + cg * 16 + 8 + j]);
    }
    *(half8*)(qf + drow) = oq0;
    *(half8*)(qf + drow + 8) = oq1;

    // ---- k ----
    half8 k0 = *(const half8*)(src + DIMX);
    half8 k1 = *(const half8*)(src + DIMX + 8);
    float sk = 0.f;
    #pragma unroll
    for (int j = 0; j < 8; j++) { float a=(float)k0[j], b2=(float)k1[j]; sk += a*a + b2*b2; }
    sk += __shfl_xor(sk, 1); sk += __shfl_xor(sk, 2);
    float ks = 8.0f / fmaxf(sqrtf(sk), 1e-12f);
    half8 ok0, ok1;
    #pragma unroll
    for (int j = 0; j < 8; j++) {
        ok0[j] = (_Float16)((float)k0[j] * ks * kg[h * 64 + cg * 16 + j]);
        ok1[j] = (_Float16)((float)k1[j] * ks * kg[h * 64 + cg * 16 + 8 + j]);
    }
    *(half8*)(kf + drow) = ok0;
    *(half8*)(kf + drow + 8) = ok1;

    // ---- v transpose ----
    half8 v0 = *(const half8*)(src + 2 * DIMX);
    half8 v1 = *(const half8*)(src + 2 * DIMX + 8);
    #pragma unroll
    for (int j = 0; j < 8; j++) tile[cg * 16 + j][r] = v0[j];
    #pragma unroll
    for (int j = 0; j < 8; j++) tile[cg * 16 + 8 + j][r] = v1[j];
    __syncthreads();
    int d = t >> 2, ng = t & 3;
    half8 w0, w1;
    #pragma unroll
    for (int j = 0; j < 8; j++) { w0[j] = tile[d][ng * 16 + j]; w1[j] = tile[d][ng * 16 + 8 + j]; }
    _Float16* vdst = vt + ((size_t)blk * 64 + d) * 64 + ng * 16;
    *(half8*)vdst = w0;
    *(half8*)(vdst + 8) = w1;
}

// ---------------------------------------------------------------------------
// Kernel 5: flash attention, transposed dataflow. S^T = K Q^T, O^T = V^T P^T.
// Lane owns ONE q-row (col=l16): row-max = 15 intra-lane fmax + 2 shuffles;
// P^T stored with 4x ds_write_b64; O^T epilogue 4x 8B global stores.
// Block = (bh, 128 q-rows); 4 waves x 2 strips of 16 rows.
// ---------------------------------------------------------------------------
__global__ __launch_bounds__(256) void flash_kernel(const _Float16* __restrict__ qf,
                                                    const _Float16* __restrict__ kf,
                                                    const _Float16* __restrict__ vt,
                                                    _Float16* __restrict__ obuf) {
    __shared__ _Float16 Ks[64 * 64];       // [kcol][dh], group-swizzled
    __shared__ _Float16 VTs[64 * 64];      // [dh][kcol], group-swizzled
    __shared__ _Float16 Ps[4][16][72];     // per-wave P^T as [qrow][kcol]

    int t = threadIdx.x;
    int wave = t >> 6, lane = t & 63;
    int quad = lane >> 4, l16 = lane & 15;
    int bh = blockIdx.x >> 3, qt = blockIdx.x & 7;

    const _Float16* qb = qf + ((size_t)bh * 1024 + qt * 128) * 64;
    const _Float16* kb = kf + (size_t)bh * 65536;
    const _Float16* vb = vt + (size_t)bh * 65536;

    // Q B-frags (n = l16 = qrow, k = quad*8+j)
    half8 aq[2][2];
    #pragma unroll
    for (int st = 0; st < 2; st++) {
        const _Float16* qrow = qb + (wave * 32 + st * 16 + l16) * 64;
        aq[st][0] = *(const half8*)(qrow + quad * 8);
        aq[st][1] = *(const half8*)(qrow + 32 + quad * 8);
    }

    floatx4 o[2][4] = {};      // O^T: [strip][dh-tile], col=l16=qrow
    float m_i[2] = {-INFINITY, -INFINITY};
    float l_i[2] = {0.f, 0.f};

    int sr = t >> 3;          // 0..31
    int sg = t & 7;
    int swz = sg ^ (sr & 7);
    char* lK = (char*)Ks  + (t >> 6) * 1024;
    char* lV = (char*)VTs + (t >> 6) * 1024;

    for (int kt = 0; kt < 16; kt++) {
        const _Float16* kbt = kb + (size_t)kt * 64 * 64;
        const _Float16* vbt = vb + (size_t)kt * 64 * 64;
        #pragma unroll
        for (int i = 0; i < 2; i++) {
            GLD_LDS16(kbt + (i * 32 + sr) * 64 + swz * 8, lK + i * 4096);
            GLD_LDS16(vbt + (i * 32 + sr) * 64 + swz * 8, lV + i * 4096);
        }
        __syncthreads();

        #pragma unroll
        for (int st = 0; st < 2; st++) {
            // S^T = K Q^T: C rows = kcol (nf*16+quad*4+r), col = qrow (l16)
            floatx4 sc[4] = {};
            #pragma unroll
            for (int kc = 0; kc < 2; kc++) {
                #pragma unroll
                for (int nf = 0; nf < 4; nf++) {
                    half8 ak = *(const half8*)&Ks[(nf * 16 + l16) * 64
                                    + (((kc * 4 + quad) ^ (l16 & 7)) * 8)];
                    sc[nf] = __builtin_amdgcn_mfma_f32_16x16x32_f16(
                        ak, aq[st][kc], sc[nf], 0, 0, 0);
                }
            }

            // online softmax: lane owns one q-row
            float mx = sc[0][0];
            #pragma unroll
            for (int nf = 0; nf < 4; nf++)
                #pragma unroll
                for (int r = 0; r < 4; r++) mx = fmaxf(mx, sc[nf][r]);
            mx = fmaxf(mx, __shfl_xor(mx, 16));
            mx = fmaxf(mx, __shfl_xor(mx, 32));
            float mnew = fmaxf(m_i[st], mx);
            float alpha = __expf(m_i[st] - mnew);
            m_i[st] = mnew;
            float psum = 0.f;
            #pragma unroll
            for (int nf = 0; nf < 4; nf++)
                #pragma unroll
                for (int r = 0; r < 4; r++) {
                    float p = __expf(sc[nf][r] - mnew);
                    sc[nf][r] = p;
                    psum += p;
                }
            l_i[st] = l_i[st] * alpha + psum;   // per-lane partial (this quad's kcols)
            #pragma unroll
            for (int nf = 0; nf < 4; nf++) o[st][nf] *= alpha;

            // P^T -> LDS: rows of S^T-tile contiguous in kcol -> b64 writes
            #pragma unroll
            for (int nf = 0; nf < 4; nf++) {
                half4 p4;
                #pragma unroll
                for (int r = 0; r < 4; r++) p4[r] = (_Float16)sc[nf][r];
                *(half4*)&Ps[wave][l16][nf * 16 + quad * 4] = p4;
            }

            // O^T += V^T P^T
            #pragma unroll
            for (int kc = 0; kc < 2; kc++) {
                half8 bp = *(const half8*)&Ps[wave][l16][kc * 32 + quad * 8];
                #pragma unroll
                for (int nf = 0; nf < 4; nf++) {
                    half8 av = *(const half8*)&VTs[(nf * 16 + l16) * 64
                                    + (((kc * 4 + quad) ^ (l16 & 7)) * 8)];
                    o[st][nf] = __builtin_amdgcn_mfma_f32_16x16x32_f16(
                        av, bp, o[st][nf], 0, 0, 0);
                }
            }
        }
        __syncthreads();
    }

    // epilogue: finish l across quads, normalize, write O (4x 8B per strip)
    int b = bh >> 4, h = bh & 15;
    #pragma unroll
    for (int st = 0; st < 2; st++) {
        float lsum = l_i[st];
        lsum += __shfl_xor(lsum, 16);
        lsum += __shfl_xor(lsum, 32);
        float inv = 1.0f / lsum;
        size_t row = (size_t)b * NSEQ + qt * 128 + wave * 32 + st * 16 + l16;
        #pragma unroll
        for (int nf = 0; nf < 4; nf++) {
            half4 o4;
            #pragma unroll
            for (int r = 0; r < 4; r++) o4[r] = (_Float16)(o[st][nf][r] * inv);
            *(half4*)(obuf + row * 1024 + h * 64 + nf * 16 + quad * 4) = o4;
        }
    }
}

// ---------------------------------------------------------------------------
extern "C" void kernel_launch(void* const* d_in, const int* in_sizes, int n_in,
                              void* d_out, int out_size, void* d_ws, size_t ws_size,
                              hipStream_t stream) {
    const float* x     = (const float*)d_in[0];
    const float* ln_g  = (const float*)d_in[1];
    const float* q_g   = (const float*)d_in[2];
    const float* k_g   = (const float*)d_in[3];
    const float* w_qkv = (const float*)d_in[4];
    const float* w_out = (const float*)d_in[5];
    float* out = (float*)d_out;

    // workspace (128 MB):
    //   [0,16)    xn fp16 / obuf fp16 (aliased; xn dead before flash writes)
    //   [16,64)   qkv fp16 (48 MB)
    //   [64,70)   wqkvT fp16 (6 MB)
    //   [72,74)   woutT fp16 (2 MB)
    //   [80,96)   qf, [96,112) kf, [112,128) vt
    char* base = (char*)d_ws;
    _Float16* xn    = (_Float16*)(base);
    _Float16* obuf  = (_Float16*)(base);
    _Float16* qkv   = (_Float16*)(base + (16ull << 20));
    _Float16* wqkvT = (_Float16*)(base + (64ull << 20));
    _Float16* woutT = (_Float16*)(base + (72ull << 20));
    _Float16* qf    = (_Float16*)(base + (80ull << 20));
    _Float16* kf    = (_Float16*)(base + (96ull << 20));
    _Float16* vt    = (_Float16*)(base + (112ull << 20));

    ln_kernel<<<ROWS, 256, 0, stream>>>(x, ln_g, xn);

    dim3 gt1(QKVW / 32, DIMX / 32);
    wtrans<<<gt1, 256, 0, stream>>>(w_qkv, wqkvT, DIMX, QKVW);

    dim3 g1(QKVW / 128, ROWS / 128);
    hgemm<_Float16><<<g1, 256, 0, stream>>>(xn, wqkvT, qkv, ROWS, QKVW, DIMX);

    rmsvt<<<NB * HEADS * (NSEQ / 64), 256, 0, stream>>>(qkv, q_g, k_g, qf, kf, vt);

    dim3 gt2(DIMX / 32, DIMX / 32);
    wtrans<<<gt2, 256, 0, stream>>>(w_out, woutT, DIMX, DIMX);

    flash_kernel<<<NB * HEADS * (NSEQ / 128), 256, 0, stream>>>(qf, kf, vt, obuf);

    dim3 g2(DIMX / 128, ROWS / 128);
    hgemm<float><<<g2, 256, 0, stream>>>(obuf, woutT, out, ROWS, DIMX, DIMX);
}

// Round 5
// 270.649 us; speedup vs baseline: 5.5563x; 1.0666x over previous
//
#include <hip/hip_runtime.h>
#include <hip/hip_bf16.h>
#include <math.h>

#define DIMX   1024
#define HEADS  16
#define DH     64
#define NB     8
#define NSEQ   1024
#define ROWS   (NB * NSEQ)        // 8192
#define QKVW   (3 * DIMX)         // 3072
#define LOG2E  1.44269504088896f

typedef _Float16 half8 __attribute__((ext_vector_type(8)));
typedef _Float16 half4 __attribute__((ext_vector_type(4)));
typedef float floatx4 __attribute__((ext_vector_type(4)));

// async global->LDS, 16B per lane. lptr must be wave-uniform; HW adds lane*16.
#define GLD_LDS16(gptr, lptr) __builtin_amdgcn_global_load_lds( \
    (const __attribute__((address_space(1))) void*)(gptr),      \
    (__attribute__((address_space(3))) void*)(lptr), 16, 0, 0)

__device__ __forceinline__ float fexp2(float x) {
#if __has_builtin(__builtin_amdgcn_exp2f)
    return __builtin_amdgcn_exp2f(x);
#else
    return __expf(x * 0.69314718056f);
#endif
}

// ---------------------------------------------------------------------------
// Kernel 1: LayerNorm -> fp16. One block (256 thr) per row of 1024.
// ---------------------------------------------------------------------------
__global__ __launch_bounds__(256) void ln_kernel(const float* __restrict__ x,
                                                 const float* __restrict__ gamma,
                                                 _Float16* __restrict__ xn) {
    int row = blockIdx.x;
    const float* xr = x + (size_t)row * DIMX;
    _Float16* xo = xn + (size_t)row * DIMX;
    int t = threadIdx.x;

    float4 v = ((const float4*)xr)[t];
    float s  = v.x + v.y + v.z + v.w;
    float ss = v.x*v.x + v.y*v.y + v.z*v.z + v.w*v.w;

    #pragma unroll
    for (int o = 32; o > 0; o >>= 1) {
        s  += __shfl_down(s, o);
        ss += __shfl_down(ss, o);
    }
    __shared__ float sbuf[4], ssbuf[4];
    int lane = t & 63, wid = t >> 6;
    if (lane == 0) { sbuf[wid] = s; ssbuf[wid] = ss; }
    __syncthreads();
    if (t == 0) {
        float a = 0.f, b2 = 0.f;
        for (int i = 0; i < 4; i++) { a += sbuf[i]; b2 += ssbuf[i]; }
        sbuf[0] = a; ssbuf[0] = b2;
    }
    __syncthreads();
    float mean = sbuf[0] * (1.0f / DIMX);
    float var  = ssbuf[0] * (1.0f / DIMX) - mean * mean;
    float rstd = rsqrtf(var + 1e-5f);

    float4 g = ((const float4*)gamma)[t];
    half4 o;
    o.x = (_Float16)((v.x - mean) * rstd * g.x);
    o.y = (_Float16)((v.y - mean) * rstd * g.y);
    o.z = (_Float16)((v.z - mean) * rstd * g.z);
    o.w = (_Float16)((v.w - mean) * rstd * g.w);
    *(half4*)(xo + t * 4) = o;
}

// ---------------------------------------------------------------------------
// Kernel 2: combined weight transpose fp32 [1024][N] -> fp16 [N][1024]
// grid.x: 0..95 -> w_qkv (N=3072), 96..127 -> w_out (N=1024)
// ---------------------------------------------------------------------------
__global__ __launch_bounds__(256) void wtrans2(const float* __restrict__ Wq,
                                               const float* __restrict__ Wo,
                                               _Float16* __restrict__ WqT,
                                               _Float16* __restrict__ WoT) {
    __shared__ float tile[32][33];
    const float* W; _Float16* WT; int N, n0;
    if (blockIdx.x < 96) { W = Wq; WT = WqT; N = QKVW; n0 = blockIdx.x * 32; }
    else                 { W = Wo; WT = WoT; N = DIMX; n0 = (blockIdx.x - 96) * 32; }
    int k0 = blockIdx.y * 32;
    int tx = threadIdx.x & 31, ty = threadIdx.x >> 5;  // 32 x 8
    #pragma unroll
    for (int i = 0; i < 32; i += 8)
        tile[ty + i][tx] = W[(size_t)(k0 + ty + i) * N + n0 + tx];
    __syncthreads();
    #pragma unroll
    for (int i = 0; i < 32; i += 8)
        WT[(size_t)(n0 + ty + i) * 1024 + k0 + tx] = (_Float16)tile[tx][ty + i];
}

// ---------------------------------------------------------------------------
// Kernel 3: fused QKV GEMM + RMS(q,k) + per-head repack.
// C = xn @ wqkvT^T computed as C^T fragments (operand-swapped MFMA) so each
// wave's 64x64 subtile = one head x 64 tokens, full dh per token in-wave.
// q: *qs*qgamma*LOG2E -> qf[bh][tok][64]; k: *ks*kgamma -> kf; v: raw -> vraw.
// ---------------------------------------------------------------------------
__global__ __launch_bounds__(256) void hgemm_qkv(const _Float16* __restrict__ A,
                                                 const _Float16* __restrict__ BT,
                                                 const float* __restrict__ qg,
                                                 const float* __restrict__ kg,
                                                 _Float16* __restrict__ qf,
                                                 _Float16* __restrict__ kf,
                                                 _Float16* __restrict__ vraw) {
    __shared__ _Float16 As[128 * 64];
    __shared__ _Float16 Bs[128 * 64];
    const int K = DIMX;

    int t = threadIdx.x;
    int wave = t >> 6, lane = t & 63;
    int quad = lane >> 4, l16 = lane & 15;
    int wm = (wave >> 1) * 64;           // token offset within tile
    int wn = (wave & 1) * 64;            // feature offset within tile
    size_t m0 = (size_t)blockIdx.y * 128, n0 = (size_t)blockIdx.x * 128;

    floatx4 acc[4][4] = {};   // D = C^T frags: row=feature, col=token(l16)

    int sr = t >> 3, sg = t & 7;
    int swz = sg ^ (sr & 7);
    const _Float16* ag = A  + (m0 + sr) * (size_t)K + swz * 8;
    const _Float16* bg = BT + (n0 + sr) * (size_t)K + swz * 8;
    char* lA = (char*)As + (t >> 6) * 1024;
    char* lB = (char*)Bs + (t >> 6) * 1024;

    for (int k0 = 0; k0 < K; k0 += 64) {
        #pragma unroll
        for (int i = 0; i < 4; i++) {
            GLD_LDS16(ag + (size_t)(i * 32) * K + k0, lA + i * 4096);
            GLD_LDS16(bg + (size_t)(i * 32) * K + k0, lB + i * 4096);
        }
        __syncthreads();

        half8 af[2][4], bf[2][4];
        #pragma unroll
        for (int kk = 0; kk < 2; kk++) {
            #pragma unroll
            for (int mf = 0; mf < 4; mf++)
                af[kk][mf] = *(const half8*)&As[(wm + mf * 16 + l16) * 64
                                 + (((kk * 4 + quad) ^ (l16 & 7)) * 8)];
            #pragma unroll
            for (int nf = 0; nf < 4; nf++)
                bf[kk][nf] = *(const half8*)&Bs[(wn + nf * 16 + l16) * 64
                                 + (((kk * 4 + quad) ^ (l16 & 7)) * 8)];
        }

        #pragma unroll
        for (int kk = 0; kk < 2; kk++)
            #pragma unroll
            for (int mf = 0; mf < 4; mf++)
                #pragma unroll
                for (int nf = 0; nf < 4; nf++)
                    acc[mf][nf] = __builtin_amdgcn_mfma_f32_16x16x32_f16(
                        bf[kk][nf], af[kk][mf], acc[mf][nf], 0, 0, 0);
        __syncthreads();
    }

    // epilogue: which = 0:q 1:k 2:v (block-uniform)
    int which = (int)(n0 >> 10);
    int nloc  = ((int)n0 & 1023) + wn;   // feature offset within q/k/v
    int h = nloc >> 6;
    const float* g = (which == 0) ? qg : kg;
    float emul = (which == 0) ? LOG2E : 1.0f;
    _Float16* dstbuf = (which == 0) ? qf : (which == 1) ? kf : vraw;

    #pragma unroll
    for (int mf = 0; mf < 4; mf++) {
        size_t tok = m0 + wm + mf * 16 + l16;
        int b = (int)(tok >> 10), ntk = (int)(tok & 1023);
        _Float16* dst = dstbuf + (((size_t)(b * 16 + h)) * 1024 + ntk) * 64;
        if (which < 2) {
            float ss = 0.f;
            #pragma unroll
            for (int nf = 0; nf < 4; nf++)
                #pragma unroll
                for (int r = 0; r < 4; r++) ss += acc[mf][nf][r] * acc[mf][nf][r];
            ss += __shfl_xor(ss, 16);
            ss += __shfl_xor(ss, 32);
            float scale = 8.0f * emul / fmaxf(sqrtf(ss), 1e-12f);
            #pragma unroll
            for (int nf = 0; nf < 4; nf++) {
                half4 p;
                #pragma unroll
                for (int r = 0; r < 4; r++)
                    p[r] = (_Float16)(acc[mf][nf][r] * scale *
                                      g[h * 64 + nf * 16 + quad * 4 + r]);
                *(half4*)(dst + nf * 16 + quad * 4) = p;
            }
        } else {
            #pragma unroll
            for (int nf = 0; nf < 4; nf++) {
                half4 p;
                #pragma unroll
                for (int r = 0; r < 4; r++) p[r] = (_Float16)acc[mf][nf][r];
                *(half4*)(dst + nf * 16 + quad * 4) = p;
            }
        }
    }
}

// ---------------------------------------------------------------------------
// Kernel 4: V transpose: vraw[bh][n][64] -> vt[bh][nt][d][n64]
// ---------------------------------------------------------------------------
__global__ __launch_bounds__(256) void vtrans(const _Float16* __restrict__ vraw,
                                              _Float16* __restrict__ vt) {
    __shared__ _Float16 tile[64][72];
    int blk = blockIdx.x;              // bh*16 + nt
    int bh = blk >> 4, nt = blk & 15;
    int t = threadIdx.x;
    int r = t >> 2, cg = t & 3;

    const _Float16* src = vraw + ((size_t)bh * 1024 + nt * 64 + r) * 64 + cg * 16;
    half8 v0 = *(const half8*)src;
    half8 v1 = *(const half8*)(src + 8);
    #pragma unroll
    for (int j = 0; j < 8; j++) tile[cg * 16 + j][r] = v0[j];
    #pragma unroll
    for (int j = 0; j < 8; j++) tile[cg * 16 + 8 + j][r] = v1[j];
    __syncthreads();
    int d = t >> 2, ng = t & 3;
    half8 w0, w1;
    #pragma unroll
    for (int j = 0; j < 8; j++) { w0[j] = tile[d][ng * 16 + j]; w1[j] = tile[d][ng * 16 + 8 + j]; }
    _Float16* vdst = vt + ((size_t)blk * 64 + d) * 64 + ng * 16;
    *(half8*)vdst = w0;
    *(half8*)(vdst + 8) = w1;
}

// ---------------------------------------------------------------------------
// Kernel 5: flash attention, transposed dataflow, exp2 softmax.
// qf is pre-scaled by LOG2E. Lane owns one q-row. Conditional o-rescale.
// ---------------------------------------------------------------------------
__global__ __launch_bounds__(256) void flash_kernel(const _Float16* __restrict__ qf,
                                                    const _Float16* __restrict__ kf,
                                                    const _Float16* __restrict__ vt,
                                                    _Float16* __restrict__ obuf) {
    __shared__ _Float16 Ks[64 * 64];       // [kcol][dh], group-swizzled
    __shared__ _Float16 VTs[64 * 64];      // [dh][kcol], group-swizzled
    __shared__ _Float16 Ps[4][16][68];     // per-wave P^T [qrow][kcol], Sb=34

    int t = threadIdx.x;
    int wave = t >> 6, lane = t & 63;
    int quad = lane >> 4, l16 = lane & 15;
    int bh = blockIdx.x >> 3, qt = blockIdx.x & 7;

    const _Float16* qb = qf + ((size_t)bh * 1024 + qt * 128) * 64;
    const _Float16* kb = kf + (size_t)bh * 65536;
    const _Float16* vb = vt + (size_t)bh * 65536;

    half8 aq[2][2];
    #pragma unroll
    for (int st = 0; st < 2; st++) {
        const _Float16* qrow = qb + (wave * 32 + st * 16 + l16) * 64;
        aq[st][0] = *(const half8*)(qrow + quad * 8);
        aq[st][1] = *(const half8*)(qrow + 32 + quad * 8);
    }

    floatx4 o[2][4] = {};
    float m_i[2] = {-INFINITY, -INFINITY};
    float l_i[2] = {0.f, 0.f};

    int sr = t >> 3;
    int sg = t & 7;
    int swz = sg ^ (sr & 7);
    char* lK = (char*)Ks  + (t >> 6) * 1024;
    char* lV = (char*)VTs + (t >> 6) * 1024;

    for (int kt = 0; kt < 16; kt++) {
        const _Float16* kbt = kb + (size_t)kt * 64 * 64;
        const _Float16* vbt = vb + (size_t)kt * 64 * 64;
        #pragma unroll
        for (int i = 0; i < 2; i++) {
            GLD_LDS16(kbt + (i * 32 + sr) * 64 + swz * 8, lK + i * 4096);
            GLD_LDS16(vbt + (i * 32 + sr) * 64 + swz * 8, lV + i * 4096);
        }
        __syncthreads();

        #pragma unroll
        for (int st = 0; st < 2; st++) {
            // S^T = K Q^T (scores already in log2 domain via qf scale)
            floatx4 sc[4] = {};
            #pragma unroll
            for (int kc = 0; kc < 2; kc++) {
                #pragma unroll
                for (int nf = 0; nf < 4; nf++) {
                    half8 ak = *(const half8*)&Ks[(nf * 16 + l16) * 64
                                    + (((kc * 4 + quad) ^ (l16 & 7)) * 8)];
                    sc[nf] = __builtin_amdgcn_mfma_f32_16x16x32_f16(
                        ak, aq[st][kc], sc[nf], 0, 0, 0);
                }
            }

            // online softmax (base-2): lane owns one q-row
            float mx = sc[0][0];
            #pragma unroll
            for (int nf = 0; nf < 4; nf++)
                #pragma unroll
                for (int r = 0; r < 4; r++) mx = fmaxf(mx, sc[nf][r]);
            mx = fmaxf(mx, __shfl_xor(mx, 16));
            mx = fmaxf(mx, __shfl_xor(mx, 32));
            if (mx > m_i[st]) {
                float alpha = fexp2(m_i[st] - mx);
                l_i[st] *= alpha;
                #pragma unroll
                for (int nf = 0; nf < 4; nf++) o[st][nf] *= alpha;
                m_i[st] = mx;
            }
            float mcur = m_i[st];
            float psum = 0.f;
            #pragma unroll
            for (int nf = 0; nf < 4; nf++)
                #pragma unroll
                for (int r = 0; r < 4; r++) {
                    float p = fexp2(sc[nf][r] - mcur);
                    sc[nf][r] = p;
                    psum += p;
                }
            l_i[st] += psum;

            // P^T -> LDS (b64 writes; stride 68 elems = 2-way-free banks)
            #pragma unroll
            for (int nf = 0; nf < 4; nf++) {
                half4 p4;
                #pragma unroll
                for (int r = 0; r < 4; r++) p4[r] = (_Float16)sc[nf][r];
                *(half4*)&Ps[wave][l16][nf * 16 + quad * 4] = p4;
            }

            // O^T += V^T P^T
            #pragma unroll
            for (int kc = 0; kc < 2; kc++) {
                half4 p0 = *(const half4*)&Ps[wave][l16][kc * 32 + quad * 8];
                half4 p1 = *(const half4*)&Ps[wave][l16][kc * 32 + quad * 8 + 4];
                half8 bp;
                #pragma unroll
                for (int j = 0; j < 4; j++) { bp[j] = p0[j]; bp[4 + j] = p1[j]; }
                #pragma unroll
                for (int nf = 0; nf < 4; nf++) {
                    half8 av = *(const half8*)&VTs[(nf * 16 + l16) * 64
                                    + (((kc * 4 + quad) ^ (l16 & 7)) * 8)];
                    o[st][nf] = __builtin_amdgcn_mfma_f32_16x16x32_f16(
                        av, bp, o[st][nf], 0, 0, 0);
                }
            }
        }
        __syncthreads();
    }

    int b = bh >> 4, h = bh & 15;
    #pragma unroll
    for (int st = 0; st < 2; st++) {
        float lsum = l_i[st];
        lsum += __shfl_xor(lsum, 16);
        lsum += __shfl_xor(lsum, 32);
        float inv = 1.0f / lsum;
        size_t row = (size_t)b * NSEQ + qt * 128 + wave * 32 + st * 16 + l16;
        #pragma unroll
        for (int nf = 0; nf < 4; nf++) {
            half4 o4;
            #pragma unroll
            for (int r = 0; r < 4; r++) o4[r] = (_Float16)(o[st][nf][r] * inv);
            *(half4*)(obuf + row * 1024 + h * 64 + nf * 16 + quad * 4) = o4;
        }
    }
}

// ---------------------------------------------------------------------------
// Kernel 6: out-projection GEMM, fp32 out, swapped epilogue -> float4 stores.
// ---------------------------------------------------------------------------
__global__ __launch_bounds__(256) void hgemm_out(const _Float16* __restrict__ A,
                                                 const _Float16* __restrict__ BT,
                                                 float* __restrict__ C) {
    __shared__ _Float16 As[128 * 64];
    __shared__ _Float16 Bs[128 * 64];
    const int K = DIMX, N = DIMX;

    int t = threadIdx.x;
    int wave = t >> 6, lane = t & 63;
    int quad = lane >> 4, l16 = lane & 15;
    int wm = (wave >> 1) * 64, wn = (wave & 1) * 64;
    size_t m0 = (size_t)blockIdx.y * 128, n0 = (size_t)blockIdx.x * 128;

    floatx4 acc[4][4] = {};

    int sr = t >> 3, sg = t & 7;
    int swz = sg ^ (sr & 7);
    const _Float16* ag = A  + (m0 + sr) * (size_t)K + swz * 8;
    const _Float16* bg = BT + (n0 + sr) * (size_t)K + swz * 8;
    char* lA = (char*)As + (t >> 6) * 1024;
    char* lB = (char*)Bs + (t >> 6) * 1024;

    for (int k0 = 0; k0 < K; k0 += 64) {
        #pragma unroll
        for (int i = 0; i < 4; i++) {
            GLD_LDS16(ag + (size_t)(i * 32) * K + k0, lA + i * 4096);
            GLD_LDS16(bg + (size_t)(i * 32) * K + k0, lB + i * 4096);
        }
        __syncthreads();

        half8 af[2][4], bf[2][4];
        #pragma unroll
        for (int kk = 0; kk < 2; kk++) {
            #pragma unroll
            for (int mf = 0; mf < 4; mf++)
                af[kk][mf] = *(const half8*)&As[(wm + mf * 16 + l16) * 64
                                 + (((kk * 4 + quad) ^ (l16 & 7)) * 8)];
            #pragma unroll
            for (int nf = 0; nf < 4; nf++)
                bf[kk][nf] = *(const half8*)&Bs[(wn + nf * 16 + l16) * 64
                                 + (((kk * 4 + quad) ^ (l16 & 7)) * 8)];
        }

        #pragma unroll
        for (int kk = 0; kk < 2; kk++)
            #pragma unroll
            for (int mf = 0; mf < 4; mf++)
                #pragma unroll
                for (int nf = 0; nf < 4; nf++)
                    acc[mf][nf] = __builtin_amdgcn_mfma_f32_16x16x32_f16(
                        bf[kk][nf], af[kk][mf], acc[mf][nf], 0, 0, 0);
        __syncthreads();
    }

    #pragma unroll
    for (int mf = 0; mf < 4; mf++) {
        size_t tok = m0 + wm + mf * 16 + l16;
        #pragma unroll
        for (int nf = 0; nf < 4; nf++)
            *(floatx4*)(C + tok * N + n0 + wn + nf * 16 + quad * 4) = acc[mf][nf];
    }
}

// ---------------------------------------------------------------------------
extern "C" void kernel_launch(void* const* d_in, const int* in_sizes, int n_in,
                              void* d_out, int out_size, void* d_ws, size_t ws_size,
                              hipStream_t stream) {
    const float* x     = (const float*)d_in[0];
    const float* ln_g  = (const float*)d_in[1];
    const float* q_g   = (const float*)d_in[2];
    const float* k_g   = (const float*)d_in[3];
    const float* w_qkv = (const float*)d_in[4];
    const float* w_out = (const float*)d_in[5];
    float* out = (float*)d_out;

    // workspace (104 MB):
    //   [0,16)   xn fp16      [16,22) wqkvT   [22,24) woutT
    //   [24,40)  qf  [40,56) kf  [56,72) vraw  [72,88) vt  [88,104) obuf
    char* base = (char*)d_ws;
    _Float16* xn    = (_Float16*)(base);
    _Float16* wqkvT = (_Float16*)(base + (16ull << 20));
    _Float16* woutT = (_Float16*)(base + (22ull << 20));
    _Float16* qf    = (_Float16*)(base + (24ull << 20));
    _Float16* kf    = (_Float16*)(base + (40ull << 20));
    _Float16* vraw  = (_Float16*)(base + (56ull << 20));
    _Float16* vt    = (_Float16*)(base + (72ull << 20));
    _Float16* obuf  = (_Float16*)(base + (88ull << 20));

    ln_kernel<<<ROWS, 256, 0, stream>>>(x, ln_g, xn);

    dim3 gt(128, 32);
    wtrans2<<<gt, 256, 0, stream>>>(w_qkv, w_out, wqkvT, woutT);

    dim3 g1(QKVW / 128, ROWS / 128);
    hgemm_qkv<<<g1, 256, 0, stream>>>(xn, wqkvT, q_g, k_g, qf, kf, vraw);

    vtrans<<<NB * HEADS * (NSEQ / 64), 256, 0, stream>>>(vraw, vt);

    flash_kernel<<<NB * HEADS * (NSEQ / 128), 256, 0, stream>>>(qf, kf, vt, obuf);

    dim3 g2(DIMX / 128, ROWS / 128);
    hgemm_out<<<g2, 256, 0, stream>>>(obuf, woutT, out);
}

// Round 6
// 250.000 us; speedup vs baseline: 6.0152x; 1.0826x over previous
//
#include <hip/hip_runtime.h>
#include <hip/hip_bf16.h>
#include <math.h>

#define DIMX   1024
#define HEADS  16
#define DH     64
#define NB     8
#define NSEQ   1024
#define ROWS   (NB * NSEQ)        // 8192
#define QKVW   (3 * DIMX)         // 3072
#define LOG2E  1.44269504088896f

typedef _Float16 half8 __attribute__((ext_vector_type(8)));
typedef _Float16 half4 __attribute__((ext_vector_type(4)));
typedef float floatx4 __attribute__((ext_vector_type(4)));

// async global->LDS, 16B per lane. lptr must be wave-uniform; HW adds lane*16.
#define GLD_LDS16(gptr, lptr) __builtin_amdgcn_global_load_lds( \
    (const __attribute__((address_space(1))) void*)(gptr),      \
    (__attribute__((address_space(3))) void*)(lptr), 16, 0, 0)

__device__ __forceinline__ float fexp2(float x) {
#if __has_builtin(__builtin_amdgcn_exp2f)
    return __builtin_amdgcn_exp2f(x);
#else
    return __expf(x * 0.69314718056f);
#endif
}

// ---------------------------------------------------------------------------
// Kernel 1: merged LayerNorm (blocks 0..8191) + weight transpose (8192..12287)
// ---------------------------------------------------------------------------
__global__ __launch_bounds__(256) void lnw_kernel(const float* __restrict__ x,
                                                  const float* __restrict__ gamma,
                                                  const float* __restrict__ Wq,
                                                  const float* __restrict__ Wo,
                                                  _Float16* __restrict__ xn,
                                                  _Float16* __restrict__ WqT,
                                                  _Float16* __restrict__ WoT) {
    __shared__ float tile[32][33];
    __shared__ float sbuf[4], ssbuf[4];
    int t = threadIdx.x;

    if (blockIdx.x < ROWS) {
        int row = blockIdx.x;
        const float* xr = x + (size_t)row * DIMX;
        _Float16* xo = xn + (size_t)row * DIMX;

        float4 v = ((const float4*)xr)[t];
        float s  = v.x + v.y + v.z + v.w;
        float ss = v.x*v.x + v.y*v.y + v.z*v.z + v.w*v.w;
        #pragma unroll
        for (int o = 32; o > 0; o >>= 1) {
            s  += __shfl_down(s, o);
            ss += __shfl_down(ss, o);
        }
        int lane = t & 63, wid = t >> 6;
        if (lane == 0) { sbuf[wid] = s; ssbuf[wid] = ss; }
        __syncthreads();
        if (t == 0) {
            float a = 0.f, b2 = 0.f;
            for (int i = 0; i < 4; i++) { a += sbuf[i]; b2 += ssbuf[i]; }
            sbuf[0] = a; ssbuf[0] = b2;
        }
        __syncthreads();
        float mean = sbuf[0] * (1.0f / DIMX);
        float var  = ssbuf[0] * (1.0f / DIMX) - mean * mean;
        float rstd = rsqrtf(var + 1e-5f);

        float4 g = ((const float4*)gamma)[t];
        half4 o;
        o.x = (_Float16)((v.x - mean) * rstd * g.x);
        o.y = (_Float16)((v.y - mean) * rstd * g.y);
        o.z = (_Float16)((v.z - mean) * rstd * g.z);
        o.w = (_Float16)((v.w - mean) * rstd * g.w);
        *(half4*)(xo + t * 4) = o;
    } else {
        int idx = blockIdx.x - ROWS;       // 0..4095
        int bx = idx & 127, by = idx >> 7; // 128 x 32
        const float* W; _Float16* WT; int N, n0;
        if (bx < 96) { W = Wq; WT = WqT; N = QKVW; n0 = bx * 32; }
        else         { W = Wo; WT = WoT; N = DIMX; n0 = (bx - 96) * 32; }
        int k0 = by * 32;
        int tx = t & 31, ty = t >> 5;      // 32 x 8
        #pragma unroll
        for (int i = 0; i < 32; i += 8)
            tile[ty + i][tx] = W[(size_t)(k0 + ty + i) * N + n0 + tx];
        __syncthreads();
        #pragma unroll
        for (int i = 0; i < 32; i += 8)
            WT[(size_t)(n0 + ty + i) * 1024 + k0 + tx] = (_Float16)tile[tx][ty + i];
    }
}

// ---------------------------------------------------------------------------
// Kernel 2: fused QKV GEMM + RMS(q,k) + per-head repack + V-transpose-store.
// Operand-swapped MFMA: wave subtile = one head x 64 tokens, full dh in-wave.
// q -> qf (scaled by LOG2E), k -> kf, v -> vt[bh][nt][d][n64] (direct scatter).
// ---------------------------------------------------------------------------
__global__ __launch_bounds__(256) void hgemm_qkv(const _Float16* __restrict__ A,
                                                 const _Float16* __restrict__ BT,
                                                 const float* __restrict__ qg,
                                                 const float* __restrict__ kg,
                                                 _Float16* __restrict__ qf,
                                                 _Float16* __restrict__ kf,
                                                 _Float16* __restrict__ vt) {
    __shared__ _Float16 As[128 * 64];
    __shared__ _Float16 Bs[128 * 64];
    const int K = DIMX;

    int t = threadIdx.x;
    int wave = t >> 6, lane = t & 63;
    int quad = lane >> 4, l16 = lane & 15;
    int wm = (wave >> 1) * 64;           // token offset within tile
    int wn = (wave & 1) * 64;            // feature offset within tile
    size_t m0 = (size_t)blockIdx.y * 128, n0 = (size_t)blockIdx.x * 128;

    floatx4 acc[4][4] = {};   // C^T frags: row=feature(nf,quad,r), col=token(mf,l16)

    int sr = t >> 3, sg = t & 7;
    int swz = sg ^ (sr & 7);
    const _Float16* ag = A  + (m0 + sr) * (size_t)K + swz * 8;
    const _Float16* bg = BT + (n0 + sr) * (size_t)K + swz * 8;
    char* lA = (char*)As + wave * 1024;
    char* lB = (char*)Bs + wave * 1024;

    for (int k0 = 0; k0 < K; k0 += 64) {
        #pragma unroll
        for (int i = 0; i < 4; i++) {
            GLD_LDS16(ag + (size_t)(i * 32) * K + k0, lA + i * 4096);
            GLD_LDS16(bg + (size_t)(i * 32) * K + k0, lB + i * 4096);
        }
        __syncthreads();

        half8 af[2][4], bf[2][4];
        #pragma unroll
        for (int kk = 0; kk < 2; kk++) {
            #pragma unroll
            for (int mf = 0; mf < 4; mf++)
                af[kk][mf] = *(const half8*)&As[(wm + mf * 16 + l16) * 64
                                 + (((kk * 4 + quad) ^ (l16 & 7)) * 8)];
            #pragma unroll
            for (int nf = 0; nf < 4; nf++)
                bf[kk][nf] = *(const half8*)&Bs[(wn + nf * 16 + l16) * 64
                                 + (((kk * 4 + quad) ^ (l16 & 7)) * 8)];
        }

        #pragma unroll
        for (int kk = 0; kk < 2; kk++)
            #pragma unroll
            for (int mf = 0; mf < 4; mf++)
                #pragma unroll
                for (int nf = 0; nf < 4; nf++)
                    acc[mf][nf] = __builtin_amdgcn_mfma_f32_16x16x32_f16(
                        bf[kk][nf], af[kk][mf], acc[mf][nf], 0, 0, 0);
        __syncthreads();
    }

    // epilogue: which = 0:q 1:k 2:v (block-uniform)
    int which = (int)(n0 >> 10);
    int nloc  = ((int)n0 & 1023) + wn;   // feature offset within q/k/v
    int h = nloc >> 6;

    if (which < 2) {
        const float* g = (which == 0) ? qg : kg;
        float emul = (which == 0) ? LOG2E : 1.0f;
        _Float16* dstbuf = (which == 0) ? qf : kf;
        #pragma unroll
        for (int mf = 0; mf < 4; mf++) {
            size_t tok = m0 + wm + mf * 16 + l16;
            int b = (int)(tok >> 10), ntk = (int)(tok & 1023);
            _Float16* dst = dstbuf + (((size_t)(b * 16 + h)) * 1024 + ntk) * 64;
            float ss = 0.f;
            #pragma unroll
            for (int nf = 0; nf < 4; nf++)
                #pragma unroll
                for (int r = 0; r < 4; r++) ss += acc[mf][nf][r] * acc[mf][nf][r];
            ss += __shfl_xor(ss, 16);
            ss += __shfl_xor(ss, 32);
            float scale = 8.0f * emul / fmaxf(sqrtf(ss), 1e-12f);
            #pragma unroll
            for (int nf = 0; nf < 4; nf++) {
                half4 p;
                #pragma unroll
                for (int r = 0; r < 4; r++)
                    p[r] = (_Float16)(acc[mf][nf][r] * scale *
                                      g[h * 64 + nf * 16 + quad * 4 + r]);
                *(half4*)(dst + nf * 16 + quad * 4) = p;
            }
        }
    } else {
        // V: direct transposed store. vt[((bh*16+nt)*64 + d)*64 + tl]
        // lane value acc[mf][nf][r]: d = nf*16+quad*4+r, tl = mf*16+l16.
        #pragma unroll
        for (int mf = 0; mf < 4; mf++) {
            size_t tok = m0 + wm + mf * 16 + l16;
            int b = (int)(tok >> 10), ntk = (int)(tok & 1023);
            int nt = ntk >> 6;
            _Float16* vd = vt + ((size_t)((b * 16 + h) * 16 + nt) * 64) * 64
                              + mf * 16 + l16;
            #pragma unroll
            for (int nf = 0; nf < 4; nf++)
                #pragma unroll
                for (int r = 0; r < 4; r++)
                    vd[(size_t)(nf * 16 + quad * 4 + r) * 64] =
                        (_Float16)acc[mf][nf][r];
        }
    }
}

// ---------------------------------------------------------------------------
// Kernel 3: flash attention, transposed dataflow, exp2 softmax, DOUBLE-
// BUFFERED K/V staging (one barrier/iter, next tile's DMA issued right after
// the barrier -> full compute phase of latency hiding). bh-major block
// mapping keeps all 8 q-tiles of a bh on one XCD for K/V L2 reuse.
// ---------------------------------------------------------------------------
__global__ __launch_bounds__(256, 3) void flash_kernel(const _Float16* __restrict__ qf,
                                                       const _Float16* __restrict__ kf,
                                                       const _Float16* __restrict__ vt,
                                                       _Float16* __restrict__ obuf) {
    __shared__ _Float16 Ks[2][64 * 64];    // [buf][kcol][dh], group-swizzled
    __shared__ _Float16 VTs[2][64 * 64];   // [buf][dh][kcol], group-swizzled
    __shared__ _Float16 Ps[4][16][68];     // per-wave P^T [qrow][kcol], Sb=34

    int t = threadIdx.x;
    int wave = t >> 6, lane = t & 63;
    int quad = lane >> 4, l16 = lane & 15;
    int bh = blockIdx.x & 127, qt = blockIdx.x >> 7;

    const _Float16* qb = qf + ((size_t)bh * 1024 + qt * 128) * 64;
    const _Float16* kb = kf + (size_t)bh * 65536;
    const _Float16* vb = vt + (size_t)bh * 65536;

    half8 aq[2][2];
    #pragma unroll
    for (int st = 0; st < 2; st++) {
        const _Float16* qrow = qb + (wave * 32 + st * 16 + l16) * 64;
        aq[st][0] = *(const half8*)(qrow + quad * 8);
        aq[st][1] = *(const half8*)(qrow + 32 + quad * 8);
    }

    floatx4 o[2][4] = {};
    float m_i[2] = {-INFINITY, -INFINITY};
    float l_i[2] = {0.f, 0.f};

    int sr = t >> 3;
    int sg = t & 7;
    int swz = sg ^ (sr & 7);

    // prologue: tile 0 -> buffer 0
    #pragma unroll
    for (int i = 0; i < 2; i++) {
        GLD_LDS16(kb + (i * 32 + sr) * 64 + swz * 8, (char*)Ks[0]  + wave * 1024 + i * 4096);
        GLD_LDS16(vb + (i * 32 + sr) * 64 + swz * 8, (char*)VTs[0] + wave * 1024 + i * 4096);
    }

    for (int kt = 0; kt < 16; kt++) {
        int cur = kt & 1;
        __syncthreads();   // drains cur's DMA (in flight for a full compute phase)

        if (kt < 15) {
            const _Float16* kn = kb + (size_t)(kt + 1) * 4096;
            const _Float16* vn = vb + (size_t)(kt + 1) * 4096;
            #pragma unroll
            for (int i = 0; i < 2; i++) {
                GLD_LDS16(kn + (i * 32 + sr) * 64 + swz * 8,
                          (char*)Ks[cur ^ 1]  + wave * 1024 + i * 4096);
                GLD_LDS16(vn + (i * 32 + sr) * 64 + swz * 8,
                          (char*)VTs[cur ^ 1] + wave * 1024 + i * 4096);
            }
        }

        #pragma unroll
        for (int st = 0; st < 2; st++) {
            // S^T = K Q^T (log2-domain scores; qf pre-scaled by LOG2E)
            floatx4 sc[4] = {};
            #pragma unroll
            for (int kc = 0; kc < 2; kc++) {
                #pragma unroll
                for (int nf = 0; nf < 4; nf++) {
                    half8 ak = *(const half8*)&Ks[cur][(nf * 16 + l16) * 64
                                    + (((kc * 4 + quad) ^ (l16 & 7)) * 8)];
                    sc[nf] = __builtin_amdgcn_mfma_f32_16x16x32_f16(
                        ak, aq[st][kc], sc[nf], 0, 0, 0);
                }
            }

            // online softmax (base-2): lane owns one q-row
            float mx = sc[0][0];
            #pragma unroll
            for (int nf = 0; nf < 4; nf++)
                #pragma unroll
                for (int r = 0; r < 4; r++) mx = fmaxf(mx, sc[nf][r]);
            mx = fmaxf(mx, __shfl_xor(mx, 16));
            mx = fmaxf(mx, __shfl_xor(mx, 32));
            if (mx > m_i[st]) {
                float alpha = fexp2(m_i[st] - mx);
                l_i[st] *= alpha;
                #pragma unroll
                for (int nf = 0; nf < 4; nf++) o[st][nf] *= alpha;
                m_i[st] = mx;
            }
            float mcur = m_i[st];
            float psum = 0.f;
            #pragma unroll
            for (int nf = 0; nf < 4; nf++)
                #pragma unroll
                for (int r = 0; r < 4; r++) {
                    float p = fexp2(sc[nf][r] - mcur);
                    sc[nf][r] = p;
                    psum += p;
                }
            l_i[st] += psum;

            // P^T -> LDS (b64 writes; stride 68 elems = conflict-free)
            #pragma unroll
            for (int nf = 0; nf < 4; nf++) {
                half4 p4;
                #pragma unroll
                for (int r = 0; r < 4; r++) p4[r] = (_Float16)sc[nf][r];
                *(half4*)&Ps[wave][l16][nf * 16 + quad * 4] = p4;
            }

            // O^T += V^T P^T
            #pragma unroll
            for (int kc = 0; kc < 2; kc++) {
                half4 p0 = *(const half4*)&Ps[wave][l16][kc * 32 + quad * 8];
                half4 p1 = *(const half4*)&Ps[wave][l16][kc * 32 + quad * 8 + 4];
                half8 bp;
                #pragma unroll
                for (int j = 0; j < 4; j++) { bp[j] = p0[j]; bp[4 + j] = p1[j]; }
                #pragma unroll
                for (int nf = 0; nf < 4; nf++) {
                    half8 av = *(const half8*)&VTs[cur][(nf * 16 + l16) * 64
                                    + (((kc * 4 + quad) ^ (l16 & 7)) * 8)];
                    o[st][nf] = __builtin_amdgcn_mfma_f32_16x16x32_f16(
                        av, bp, o[st][nf], 0, 0, 0);
                }
            }
        }
    }

    int b = bh >> 4, h = bh & 15;
    #pragma unroll
    for (int st = 0; st < 2; st++) {
        float lsum = l_i[st];
        lsum += __shfl_xor(lsum, 16);
        lsum += __shfl_xor(lsum, 32);
        float inv = 1.0f / lsum;
        size_t row = (size_t)b * NSEQ + qt * 128 + wave * 32 + st * 16 + l16;
        #pragma unroll
        for (int nf = 0; nf < 4; nf++) {
            half4 o4;
            #pragma unroll
            for (int r = 0; r < 4; r++) o4[r] = (_Float16)(o[st][nf][r] * inv);
            *(half4*)(obuf + row * 1024 + h * 64 + nf * 16 + quad * 4) = o4;
        }
    }
}

// ---------------------------------------------------------------------------
// Kernel 4: out-projection GEMM, fp32 out, swapped epilogue -> float4 stores.
// ---------------------------------------------------------------------------
__global__ __launch_bounds__(256) void hgemm_out(const _Float16* __restrict__ A,
                                                 const _Float16* __restrict__ BT,
                                                 float* __restrict__ C) {
    __shared__ _Float16 As[128 * 64];
    __shared__ _Float16 Bs[128 * 64];
    const int K = DIMX, N = DIMX;

    int t = threadIdx.x;
    int wave = t >> 6, lane = t & 63;
    int quad = lane >> 4, l16 = lane & 15;
    int wm = (wave >> 1) * 64, wn = (wave & 1) * 64;
    size_t m0 = (size_t)blockIdx.y * 128, n0 = (size_t)blockIdx.x * 128;

    floatx4 acc[4][4] = {};

    int sr = t >> 3, sg = t & 7;
    int swz = sg ^ (sr & 7);
    const _Float16* ag = A  + (m0 + sr) * (size_t)K + swz * 8;
    const _Float16* bg = BT + (n0 + sr) * (size_t)K + swz * 8;
    char* lA = (char*)As + wave * 1024;
    char* lB = (char*)Bs + wave * 1024;

    for (int k0 = 0; k0 < K; k0 += 64) {
        #pragma unroll
        for (int i = 0; i < 4; i++) {
            GLD_LDS16(ag + (size_t)(i * 32) * K + k0, lA + i * 4096);
            GLD_LDS16(bg + (size_t)(i * 32) * K + k0, lB + i * 4096);
        }
        __syncthreads();

        half8 af[2][4], bf[2][4];
        #pragma unroll
        for (int kk = 0; kk < 2; kk++) {
            #pragma unroll
            for (int mf = 0; mf < 4; mf++)
                af[kk][mf] = *(const half8*)&As[(wm + mf * 16 + l16) * 64
                                 + (((kk * 4 + quad) ^ (l16 & 7)) * 8)];
            #pragma unroll
            for (int nf = 0; nf < 4; nf++)
                bf[kk][nf] = *(const half8*)&Bs[(wn + nf * 16 + l16) * 64
                                 + (((kk * 4 + quad) ^ (l16 & 7)) * 8)];
        }

        #pragma unroll
        for (int kk = 0; kk < 2; kk++)
            #pragma unroll
            for (int mf = 0; mf < 4; mf++)
                #pragma unroll
                for (int nf = 0; nf < 4; nf++)
                    acc[mf][nf] = __builtin_amdgcn_mfma_f32_16x16x32_f16(
                        bf[kk][nf], af[kk][mf], acc[mf][nf], 0, 0, 0);
        __syncthreads();
    }

    #pragma unroll
    for (int mf = 0; mf < 4; mf++) {
        size_t tok = m0 + wm + mf * 16 + l16;
        #pragma unroll
        for (int nf = 0; nf < 4; nf++)
            *(floatx4*)(C + tok * N + n0 + wn + nf * 16 + quad * 4) = acc[mf][nf];
    }
}

// ---------------------------------------------------------------------------
extern "C" void kernel_launch(void* const* d_in, const int* in_sizes, int n_in,
                              void* d_out, int out_size, void* d_ws, size_t ws_size,
                              hipStream_t stream) {
    const float* x     = (const float*)d_in[0];
    const float* ln_g  = (const float*)d_in[1];
    const float* q_g   = (const float*)d_in[2];
    const float* k_g   = (const float*)d_in[3];
    const float* w_qkv = (const float*)d_in[4];
    const float* w_out = (const float*)d_in[5];
    float* out = (float*)d_out;

    // workspace (88 MB):
    //   [0,16)  xn   [16,22) wqkvT  [22,24) woutT
    //   [24,40) qf   [40,56) kf     [56,72) vt    [72,88) obuf
    char* base = (char*)d_ws;
    _Float16* xn    = (_Float16*)(base);
    _Float16* wqkvT = (_Float16*)(base + (16ull << 20));
    _Float16* woutT = (_Float16*)(base + (22ull << 20));
    _Float16* qf    = (_Float16*)(base + (24ull << 20));
    _Float16* kf    = (_Float16*)(base + (40ull << 20));
    _Float16* vt    = (_Float16*)(base + (56ull << 20));
    _Float16* obuf  = (_Float16*)(base + (72ull << 20));

    lnw_kernel<<<ROWS + 4096, 256, 0, stream>>>(x, ln_g, w_qkv, w_out,
                                                xn, wqkvT, woutT);

    dim3 g1(QKVW / 128, ROWS / 128);
    hgemm_qkv<<<g1, 256, 0, stream>>>(xn, wqkvT, q_g, k_g, qf, kf, vt);

    flash_kernel<<<NB * HEADS * (NSEQ / 128), 256, 0, stream>>>(qf, kf, vt, obuf);

    dim3 g2(DIMX / 128, ROWS / 128);
    hgemm_out<<<g2, 256, 0, stream>>>(obuf, woutT, out);
}